// Round 1
// baseline (3500.175 us; speedup 1.0000x reference)
//
#include <hip/hip_runtime.h>
#include <hip/hip_bf16.h>

#define NN 100000
#define EE 3200000
#define HH 64
#define FIN 6
#define FOUT 5
#define NGNB 50000

static inline int cdiv(int a, int b) { return (a + b - 1) / b; }

// deg[i] = 1.0 (self loop weight)
__global__ void k_deg_init(float* __restrict__ deg) {
    int i = blockIdx.x * 256 + threadIdx.x;
    if (i < NN) deg[i] = 1.0f;
}

// deg[dst[e]] += w[e]
__global__ void k_deg_acc(const int* __restrict__ dst, const float* __restrict__ w,
                          float* __restrict__ deg) {
    int e = blockIdx.x * 256 + threadIdx.x;
    if (e < EE) atomicAdd(&deg[dst[e]], w[e]);
}

// in-place: dinv[i] = rsqrt(deg[i])   (deg >= 1 always)
__global__ void k_dinv(float* __restrict__ d) {
    int i = blockIdx.x * 256 + threadIdx.x;
    if (i < NN) d[i] = rsqrtf(d[i]);
}

// norm[e] = dinv[src]*w*dinv[dst]
__global__ void k_norm(const int* __restrict__ src, const int* __restrict__ dst,
                       const float* __restrict__ w, const float* __restrict__ dinv,
                       float* __restrict__ norm) {
    int e = blockIdx.x * 256 + threadIdx.x;
    if (e < EE) norm[e] = dinv[src[e]] * w[e] * dinv[dst[e]];
}

// acc[i,f] = x[i,f] * dinv[i]^2   (self-loop term; also serves as the zero-init)
__global__ void k_selfinit64(const float* __restrict__ x, const float* __restrict__ dinv,
                             float* __restrict__ acc) {
    int idx = blockIdx.x * 256 + threadIdx.x;  // N*64 = 6.4M
    if (idx < NN * HH) {
        float di = dinv[idx >> 6];
        acc[idx] = x[idx] * di * di;
    }
}

__global__ void k_selfinit6(const float* __restrict__ x, const float* __restrict__ dinv,
                            float* __restrict__ acc) {
    int idx = blockIdx.x * 256 + threadIdx.x;  // N*6
    if (idx < NN * FIN) {
        int i = idx / FIN;
        float di = dinv[i];
        acc[idx] = x[idx] * di * di;
    }
}

// one 64-lane wave per edge: lane = feature
__global__ void k_scatter64(const int* __restrict__ src, const int* __restrict__ dst,
                            const float* __restrict__ norm, const float* __restrict__ x,
                            float* __restrict__ acc) {
    int tid = blockIdx.x * 256 + threadIdx.x;
    int e = tid >> 6;
    int lane = threadIdx.x & 63;
    if (e >= EE) return;
    int s = src[e];
    int d = dst[e];
    float v = x[s * HH + lane] * norm[e];
    atomicAdd(&acc[d * HH + lane], v);
}

// thread per edge, 6 features
__global__ void k_scatter6(const int* __restrict__ src, const int* __restrict__ dst,
                           const float* __restrict__ norm, const float* __restrict__ x,
                           float* __restrict__ acc) {
    int e = blockIdx.x * 256 + threadIdx.x;
    if (e >= EE) return;
    int s = src[e];
    int d = dst[e];
    float nv = norm[e];
#pragma unroll
    for (int f = 0; f < FIN; ++f)
        atomicAdd(&acc[d * FIN + f], x[s * FIN + f] * nv);
}

// out[i,:] = sigmoid(acc[i,:FI] @ W[FI,64] + b),  one wave per row
template <int FI>
__global__ void k_gemm_sig(const float* __restrict__ x, const float* __restrict__ W,
                           const float* __restrict__ b, float* __restrict__ out) {
    __shared__ float Wl[FI * 64];
    __shared__ float bl[64];
    for (int t = threadIdx.x; t < FI * 64; t += 256) Wl[t] = W[t];
    if (threadIdx.x < 64) bl[threadIdx.x] = b[threadIdx.x];
    __syncthreads();
    int wave = (blockIdx.x * 256 + threadIdx.x) >> 6;
    int lane = threadIdx.x & 63;
    if (wave >= NN) return;
    const float* xr = x + (size_t)wave * FI;
    float s = bl[lane];
#pragma unroll
    for (int f = 0; f < FI; ++f) s += xr[f] * Wl[f * 64 + lane];
    out[wave * HH + lane] = 1.0f / (1.0f + __expf(-s));
}

// head: out[i,j] = x[i,:] @ Wl[:,j] + bl[j], i < NGNB, j < 5
__global__ void k_head(const float* __restrict__ x, const float* __restrict__ Wl,
                       const float* __restrict__ bl, float* __restrict__ out) {
    int tid = blockIdx.x * 256 + threadIdx.x;
    if (tid >= NGNB * FOUT) return;
    int i = tid / FOUT;
    int j = tid - i * FOUT;
    const float* xr = x + (size_t)i * HH;
    float s = bl[j];
#pragma unroll
    for (int f = 0; f < HH; ++f) s += xr[f] * Wl[f * FOUT + j];
    out[tid] = s;
}

extern "C" void kernel_launch(void* const* d_in, const int* in_sizes, int n_in,
                              void* d_out, int out_size, void* d_ws, size_t ws_size,
                              hipStream_t stream) {
    (void)in_sizes; (void)n_in; (void)out_size; (void)ws_size;
    const float* vf   = (const float*)d_in[0];       // N x 6
    const int*   edges = (const int*)d_in[1];        // (2, E)
    const float* w    = (const float*)d_in[2];       // E
    const float* W1   = (const float*)d_in[3];
    const float* b1   = (const float*)d_in[4];
    const float* W2   = (const float*)d_in[5];
    const float* b2   = (const float*)d_in[6];
    const float* W3   = (const float*)d_in[7];
    const float* b3   = (const float*)d_in[8];
    const float* W4   = (const float*)d_in[9];
    const float* b4   = (const float*)d_in[10];
    const float* Wl   = (const float*)d_in[11];
    const float* bl   = (const float*)d_in[12];
    float* out = (float*)d_out;

    const int* src = edges;
    const int* dst = edges + EE;

    float* ws   = (float*)d_ws;
    float* dinv = ws;                 // N
    float* norm = dinv + NN;          // E
    float* acc  = norm + EE;          // N*64
    float* xbuf = acc + (size_t)NN * HH;  // N*64

    // degree + norm (layer-invariant)
    k_deg_init<<<cdiv(NN, 256), 256, 0, stream>>>(dinv);
    k_deg_acc<<<cdiv(EE, 256), 256, 0, stream>>>(dst, w, dinv);
    k_dinv<<<cdiv(NN, 256), 256, 0, stream>>>(dinv);
    k_norm<<<cdiv(EE, 256), 256, 0, stream>>>(src, dst, w, dinv, norm);

    // layer 1: aggregate 6-dim input, then 6->64 GEMM + bias + sigmoid
    k_selfinit6<<<cdiv(NN * FIN, 256), 256, 0, stream>>>(vf, dinv, acc);
    k_scatter6<<<cdiv(EE, 256), 256, 0, stream>>>(src, dst, norm, vf, acc);
    k_gemm_sig<FIN><<<cdiv(NN * 64, 256), 256, 0, stream>>>(acc, W1, b1, xbuf);

    // layers 2..4: aggregate 64-dim, then 64->64 GEMM + bias + sigmoid
    const float* Ws[3] = {W2, W3, W4};
    const float* bs[3] = {b2, b3, b4};
    for (int l = 0; l < 3; ++l) {
        k_selfinit64<<<cdiv(NN * HH, 256), 256, 0, stream>>>(xbuf, dinv, acc);
        k_scatter64<<<cdiv(EE * 64, 256), 256, 0, stream>>>(src, dst, norm, xbuf, acc);
        k_gemm_sig<HH><<<cdiv(NN * 64, 256), 256, 0, stream>>>(acc, Ws[l], bs[l], xbuf);
    }

    // head
    k_head<<<cdiv(NGNB * FOUT, 256), 256, 0, stream>>>(xbuf, Wl, bl, out);
}

// Round 3
// 1763.017 us; speedup vs baseline: 1.9853x; 1.9853x over previous
//
#include <hip/hip_runtime.h>

#define NN 100000
#define EE 3200000
#define HH 64
#define FINN 6
#define FOUT 5
#define NGNB 50000
#define NBLK 391  // cdiv(NN,256)

static inline int cdiv(int a, int b) { return (a + b - 1) / b; }
static inline size_t alignup(size_t x) { return (x + 255) & ~(size_t)255; }

// deg[i]=1.0 (self loop), cnt[i]=0
__global__ void k_init(float* __restrict__ deg, int* __restrict__ cnt) {
    int i = blockIdx.x * 256 + threadIdx.x;
    if (i < NN) { deg[i] = 1.0f; cnt[i] = 0; }
}

// per-edge: in-degree count + weighted degree
__global__ void k_count(const int* __restrict__ dst, const float* __restrict__ w,
                        int* __restrict__ cnt, float* __restrict__ deg) {
    int e = blockIdx.x * 256 + threadIdx.x;
    if (e < EE) {
        int d = dst[e];
        atomicAdd(&cnt[d], 1);
        atomicAdd(&deg[d], w[e]);
    }
}

__global__ void k_dinv(float* __restrict__ d) {
    int i = blockIdx.x * 256 + threadIdx.x;
    if (i < NN) d[i] = rsqrtf(d[i]);
}

// block-level inclusive scan of cnt -> tmp; block totals -> partials
__global__ void k_scan1(const int* __restrict__ cnt, int* __restrict__ tmp,
                        int* __restrict__ partials) {
    __shared__ int sh[256];
    int t = threadIdx.x, i = blockIdx.x * 256 + t;
    int v = (i < NN) ? cnt[i] : 0;
    sh[t] = v;
    __syncthreads();
    for (int off = 1; off < 256; off <<= 1) {
        int a = (t >= off) ? sh[t - off] : 0;
        __syncthreads();
        sh[t] += a;
        __syncthreads();
    }
    if (i < NN) tmp[i] = sh[t];
    if (t == 255) partials[blockIdx.x] = sh[255];
}

// single-block exclusive scan of partials (NBLK=391 <= 512), in place
__global__ void k_scan2(int* __restrict__ partials) {
    __shared__ int sh[512];
    int t = threadIdx.x;
    int v = (t < NBLK) ? partials[t] : 0;
    sh[t] = v;
    __syncthreads();
    for (int off = 1; off < 512; off <<= 1) {
        int a = (t >= off) ? sh[t - off] : 0;
        __syncthreads();
        sh[t] += a;
        __syncthreads();
    }
    if (t < NBLK) partials[t] = sh[t] - v;  // exclusive
}

// row_ptr[i] = exclusive global scan; cursor[i] = row_ptr[i]; row_ptr[NN]=E
__global__ void k_scan3(const int* __restrict__ tmp, const int* __restrict__ partials,
                        const int* __restrict__ cnt, int* __restrict__ row_ptr,
                        int* __restrict__ cursor) {
    int i = blockIdx.x * 256 + threadIdx.x;
    if (i < NN) {
        int c = cnt[i];
        int rp = partials[blockIdx.x] + tmp[i] - c;
        row_ptr[i] = rp;
        cursor[i] = rp;
        if (i == NN - 1) row_ptr[NN] = rp + c;
    }
}

// scatter edges into CSR slots (int atomics only); norm computed here
__global__ void k_fill(const int* __restrict__ src, const int* __restrict__ dst,
                       const float* __restrict__ w, const float* __restrict__ dinv,
                       int* __restrict__ cursor, int* __restrict__ esrc,
                       float* __restrict__ enorm) {
    int e = blockIdx.x * 256 + threadIdx.x;
    if (e < EE) {
        int s = src[e], d = dst[e];
        int pos = atomicAdd(&cursor[d], 1);
        esrc[pos] = s;
        enorm[pos] = dinv[s] * w[e] * dinv[d];
    }
}

// layer-1 aggregation: thread per node, 6 features -> acc[N*6]
__global__ void k_gather6(const float* __restrict__ vf, const float* __restrict__ dinv,
                          const int* __restrict__ rp, const int* __restrict__ esrc,
                          const float* __restrict__ enorm, float* __restrict__ acc) {
    int i = blockIdx.x * 256 + threadIdx.x;
    if (i >= NN) return;
    float di = dinv[i];
    float sc = di * di;
    float av[FINN];
#pragma unroll
    for (int f = 0; f < FINN; ++f) av[f] = vf[i * FINN + f] * sc;
    int e1 = rp[i + 1];
    for (int e = rp[i]; e < e1; ++e) {
        int s = esrc[e];
        float nv = enorm[e];
#pragma unroll
        for (int f = 0; f < FINN; ++f) av[f] += vf[s * FINN + f] * nv;
    }
#pragma unroll
    for (int f = 0; f < FINN; ++f) acc[i * FINN + f] = av[f];
}

// 64-dim aggregation: wave per node, lane = feature -> acc[N*64]
__global__ __launch_bounds__(256) void k_gather64(
    const float* __restrict__ x, const float* __restrict__ dinv,
    const int* __restrict__ rp, const int* __restrict__ esrc,
    const float* __restrict__ enorm, float* __restrict__ acc) {
    int wv = threadIdx.x >> 6, lane = threadIdx.x & 63;
    int i = blockIdx.x * 4 + wv;
    if (i >= NN) return;
    float di = dinv[i];
    float agg = x[(size_t)i * HH + lane] * di * di;  // self loop
    int e1 = rp[i + 1];
    for (int e = rp[i]; e < e1; ++e) {
        agg += x[(size_t)esrc[e] * HH + lane] * enorm[e];
    }
    acc[(size_t)i * HH + lane] = agg;
}

// out[i,:] = sigmoid(acc[i,:FI] @ W[FI,64] + b),  one wave per row  (round-1 verbatim)
template <int FI>
__global__ void k_gemm_sig(const float* __restrict__ x, const float* __restrict__ W,
                           const float* __restrict__ b, float* __restrict__ out) {
    __shared__ float Wl[FI * 64];
    __shared__ float bl[64];
    for (int t = threadIdx.x; t < FI * 64; t += 256) Wl[t] = W[t];
    if (threadIdx.x < 64) bl[threadIdx.x] = b[threadIdx.x];
    __syncthreads();
    int wave = (blockIdx.x * 256 + threadIdx.x) >> 6;
    int lane = threadIdx.x & 63;
    if (wave >= NN) return;
    const float* xr = x + (size_t)wave * FI;
    float s = bl[lane];
#pragma unroll
    for (int f = 0; f < FI; ++f) s += xr[f] * Wl[f * 64 + lane];
    out[wave * HH + lane] = 1.0f / (1.0f + __expf(-s));
}

// head: out[i,j] = x[i,:] @ Wl[:,j] + bl[j]  (round-1 verbatim)
__global__ void k_head(const float* __restrict__ x, const float* __restrict__ Wl,
                       const float* __restrict__ bl, float* __restrict__ out) {
    int tid = blockIdx.x * 256 + threadIdx.x;
    if (tid >= NGNB * FOUT) return;
    int i = tid / FOUT;
    int j = tid - i * FOUT;
    const float* xr = x + (size_t)i * HH;
    float s = bl[j];
#pragma unroll
    for (int f = 0; f < HH; ++f) s += xr[f] * Wl[f * FOUT + j];
    out[tid] = s;
}

extern "C" void kernel_launch(void* const* d_in, const int* in_sizes, int n_in,
                              void* d_out, int out_size, void* d_ws, size_t ws_size,
                              hipStream_t stream) {
    (void)in_sizes; (void)n_in; (void)out_size; (void)ws_size;
    const float* vf = (const float*)d_in[0];
    const int* edges = (const int*)d_in[1];
    const float* w = (const float*)d_in[2];
    const float* W1 = (const float*)d_in[3];
    const float* b1 = (const float*)d_in[4];
    const float* W2 = (const float*)d_in[5];
    const float* b2 = (const float*)d_in[6];
    const float* W3 = (const float*)d_in[7];
    const float* b3 = (const float*)d_in[8];
    const float* W4 = (const float*)d_in[9];
    const float* b4 = (const float*)d_in[10];
    const float* Wl = (const float*)d_in[11];
    const float* bl = (const float*)d_in[12];
    float* out = (float*)d_out;

    const int* src = edges;
    const int* dst = edges + EE;

    // workspace: every region 256B-aligned, no aliasing anywhere
    char* base = (char*)d_ws;
    size_t off = 0;
    float* dinv = (float*)(base + off);     off = alignup(off + sizeof(float) * NN);
    int* row_ptr = (int*)(base + off);      off = alignup(off + sizeof(int) * (NN + 1));
    int* cursor = (int*)(base + off);       off = alignup(off + sizeof(int) * NN);
    int* tmp = (int*)(base + off);          off = alignup(off + sizeof(int) * NN);
    int* partials = (int*)(base + off);     off = alignup(off + sizeof(int) * NBLK);
    int* esrc = (int*)(base + off);         off = alignup(off + sizeof(int) * EE);
    float* enorm = (float*)(base + off);    off = alignup(off + sizeof(float) * EE);
    float* acc = (float*)(base + off);      off = alignup(off + sizeof(float) * (size_t)NN * HH);
    float* xbuf = (float*)(base + off);     off = alignup(off + sizeof(float) * (size_t)NN * HH);

    // build normalization + CSR
    k_init<<<cdiv(NN, 256), 256, 0, stream>>>(dinv, cursor);
    k_count<<<cdiv(EE, 256), 256, 0, stream>>>(dst, w, cursor, dinv);
    k_dinv<<<cdiv(NN, 256), 256, 0, stream>>>(dinv);
    k_scan1<<<NBLK, 256, 0, stream>>>(cursor, tmp, partials);
    k_scan2<<<1, 512, 0, stream>>>(partials);
    k_scan3<<<NBLK, 256, 0, stream>>>(tmp, partials, cursor, row_ptr, cursor);
    k_fill<<<cdiv(EE, 256), 256, 0, stream>>>(src, dst, w, dinv, cursor, esrc, enorm);

    // layer 1: gather(6) -> gemm+sigmoid -> xbuf
    k_gather6<<<cdiv(NN, 256), 256, 0, stream>>>(vf, dinv, row_ptr, esrc, enorm, acc);
    k_gemm_sig<FINN><<<cdiv(NN * 64, 256), 256, 0, stream>>>(acc, W1, b1, xbuf);

    // layers 2..4: gather(64) xbuf->acc, gemm acc->xbuf
    const float* Ws[3] = {W2, W3, W4};
    const float* bs[3] = {b2, b3, b4};
    for (int l = 0; l < 3; ++l) {
        k_gather64<<<cdiv(NN, 4), 256, 0, stream>>>(xbuf, dinv, row_ptr, esrc, enorm, acc);
        k_gemm_sig<HH><<<cdiv(NN * 64, 256), 256, 0, stream>>>(acc, Ws[l], bs[l], xbuf);
    }

    // head
    k_head<<<cdiv(NGNB * FOUT, 256), 256, 0, stream>>>(xbuf, Wl, bl, out);
}

// Round 4
// 1163.961 us; speedup vs baseline: 3.0071x; 1.5147x over previous
//
#include <hip/hip_runtime.h>
#include <hip/hip_fp16.h>

#define NN 100000
#define EE 3200000
#define HH 64
#define FINN 6
#define FOUT 5
#define NGNB 50000
#define NBLK 391  // cdiv(NN,256)

static inline int cdiv(int a, int b) { return (a + b - 1) / b; }
static inline size_t alignup(size_t x) { return (x + 255) & ~(size_t)255; }

// packed[i] = 0
__global__ void k_init(unsigned long long* __restrict__ packed) {
    int i = blockIdx.x * 256 + threadIdx.x;
    if (i < NN) packed[i] = 0ULL;
}

// one u64 atomic per edge: count in bits [40..63], weight-sum (2^24 fixed point) in [0..39]
__global__ void k_count(const int* __restrict__ dst, const float* __restrict__ w,
                        unsigned long long* __restrict__ packed) {
    int e = blockIdx.x * 256 + threadIdx.x;
    if (e < EE) {
        unsigned long long add =
            (1ULL << 40) | (unsigned long long)(w[e] * 16777216.0f);
        atomicAdd(&packed[dst[e]], add);
    }
}

// unpack: dinv = rsqrt(1 + wsum), cnt = count
__global__ void k_post(const unsigned long long* __restrict__ packed,
                       float* __restrict__ dinv, int* __restrict__ cnt) {
    int i = blockIdx.x * 256 + threadIdx.x;
    if (i < NN) {
        unsigned long long v = packed[i];
        float sum = (float)(v & 0xFFFFFFFFFFULL) * (1.0f / 16777216.0f);
        dinv[i] = rsqrtf(1.0f + sum);
        cnt[i] = (int)(v >> 40);
    }
}

// block-level inclusive scan of cnt -> tmp; block totals -> partials
__global__ void k_scan1(const int* __restrict__ cnt, int* __restrict__ tmp,
                        int* __restrict__ partials) {
    __shared__ int sh[256];
    int t = threadIdx.x, i = blockIdx.x * 256 + t;
    int v = (i < NN) ? cnt[i] : 0;
    sh[t] = v;
    __syncthreads();
    for (int off = 1; off < 256; off <<= 1) {
        int a = (t >= off) ? sh[t - off] : 0;
        __syncthreads();
        sh[t] += a;
        __syncthreads();
    }
    if (i < NN) tmp[i] = sh[t];
    if (t == 255) partials[blockIdx.x] = sh[255];
}

// single-block exclusive scan of partials (NBLK <= 512), in place
__global__ void k_scan2(int* __restrict__ partials) {
    __shared__ int sh[512];
    int t = threadIdx.x;
    int v = (t < NBLK) ? partials[t] : 0;
    sh[t] = v;
    __syncthreads();
    for (int off = 1; off < 512; off <<= 1) {
        int a = (t >= off) ? sh[t - off] : 0;
        __syncthreads();
        sh[t] += a;
        __syncthreads();
    }
    if (t < NBLK) partials[t] = sh[t] - v;  // exclusive
}

// row_ptr[i] = exclusive global scan; cursor[i] = row_ptr[i]; row_ptr[NN]=E
__global__ void k_scan3(const int* __restrict__ tmp, const int* __restrict__ partials,
                        const int* __restrict__ cnt, int* __restrict__ row_ptr,
                        int* __restrict__ cursor) {
    int i = blockIdx.x * 256 + threadIdx.x;
    if (i < NN) {
        int c = cnt[i];
        int rp = partials[blockIdx.x] + tmp[i] - c;
        row_ptr[i] = rp;
        cursor[i] = rp;
        if (i == NN - 1) row_ptr[NN] = rp + c;
    }
}

// scatter edges into CSR slots; epack = {src, w*dinv[src]} (dinv[dst] folded into gather)
__global__ void k_fill(const int* __restrict__ src, const int* __restrict__ dst,
                       const float* __restrict__ w, const float* __restrict__ dinv,
                       int* __restrict__ cursor, int2* __restrict__ epack) {
    int e = blockIdx.x * 256 + threadIdx.x;
    if (e < EE) {
        int s = src[e], d = dst[e];
        int pos = atomicAdd(&cursor[d], 1);
        int2 p;
        p.x = s;
        p.y = __float_as_int(w[e] * dinv[s]);
        epack[pos] = p;
    }
}

// layer-1 aggregation: thread per node, 6 features -> acc6[N*6]
// acc6[i] = dinv[i] * (dinv[i]*vf[i] + sum wn*vf[s])
__global__ void k_gather6(const float* __restrict__ vf, const float* __restrict__ dinv,
                          const int* __restrict__ rp, const int2* __restrict__ epack,
                          float* __restrict__ acc6) {
    int i = blockIdx.x * 256 + threadIdx.x;
    if (i >= NN) return;
    float di = dinv[i];
    float av[FINN];
#pragma unroll
    for (int f = 0; f < FINN; ++f) av[f] = vf[i * FINN + f] * di;
    int e1 = rp[i + 1];
    for (int e = rp[i]; e < e1; ++e) {
        int2 p = epack[e];
        float wn = __int_as_float(p.y);
#pragma unroll
        for (int f = 0; f < FINN; ++f) av[f] += vf[p.x * FINN + f] * wn;
    }
#pragma unroll
    for (int f = 0; f < FINN; ++f) acc6[i * FINN + f] = av[f] * di;
}

// 64-dim aggregation from fp16 x: wave per node. Lanes 0-31 take even edges,
// lanes 32-63 odd edges; each lane covers feature pair (lane&31); shfl-combine.
__global__ __launch_bounds__(256) void k_gather64h(
    const __half* __restrict__ xh, const float* __restrict__ dinv,
    const int* __restrict__ rp, const int2* __restrict__ epack,
    float* __restrict__ acc) {
    int wv = threadIdx.x >> 6, lane = threadIdx.x & 63;
    int i = blockIdx.x * 4 + wv;
    if (i >= NN) return;
    int hf = lane >> 5, fp = lane & 31;
    float di = dinv[i];
    float2 a = make_float2(0.0f, 0.0f);
    if (hf == 0) {  // self-loop term (inner): dinv[i] * x[i]
        float2 sv = __half22float2(((const __half2*)(xh + (size_t)i * HH))[fp]);
        a.x = sv.x * di;
        a.y = sv.y * di;
    }
    int e0 = rp[i], e1 = rp[i + 1];
    for (int e = e0 + hf; e < e1; e += 2) {
        int2 p = epack[e];
        float wn = __int_as_float(p.y);
        float2 v = __half22float2(((const __half2*)(xh + (size_t)p.x * HH))[fp]);
        a.x += v.x * wn;
        a.y += v.y * wn;
    }
    a.x += __shfl(a.x, lane ^ 32, 64);
    a.y += __shfl(a.y, lane ^ 32, 64);
    if (hf == 0) {
        float2 o;
        o.x = a.x * di;
        o.y = a.y * di;
        ((float2*)(acc + (size_t)i * HH))[fp] = o;
    }
}

// out[i,:] = sigmoid(acc[i,:FI] @ W[FI,64] + b) -> fp16,  one wave per row
template <int FI>
__global__ void k_gemm_sig(const float* __restrict__ x, const float* __restrict__ W,
                           const float* __restrict__ b, __half* __restrict__ out) {
    __shared__ float Wl[FI * 64];
    __shared__ float bl[64];
    for (int t = threadIdx.x; t < FI * 64; t += 256) Wl[t] = W[t];
    if (threadIdx.x < 64) bl[threadIdx.x] = b[threadIdx.x];
    __syncthreads();
    int wave = (blockIdx.x * 256 + threadIdx.x) >> 6;
    int lane = threadIdx.x & 63;
    if (wave >= NN) return;
    const float* xr = x + (size_t)wave * FI;
    float s = bl[lane];
#pragma unroll
    for (int f = 0; f < FI; ++f) s += xr[f] * Wl[f * 64 + lane];
    out[(size_t)wave * HH + lane] = __float2half(1.0f / (1.0f + __expf(-s)));
}

// head: out[i,j] = x[i,:] @ Wl[:,j] + bl[j]
__global__ void k_head(const __half* __restrict__ xh, const float* __restrict__ Wl,
                       const float* __restrict__ bl, float* __restrict__ out) {
    int tid = blockIdx.x * 256 + threadIdx.x;
    if (tid >= NGNB * FOUT) return;
    int i = tid / FOUT;
    int j = tid - i * FOUT;
    const __half* xr = xh + (size_t)i * HH;
    float s = bl[j];
#pragma unroll
    for (int f = 0; f < HH; ++f) s += __half2float(xr[f]) * Wl[f * FOUT + j];
    out[tid] = s;
}

extern "C" void kernel_launch(void* const* d_in, const int* in_sizes, int n_in,
                              void* d_out, int out_size, void* d_ws, size_t ws_size,
                              hipStream_t stream) {
    (void)in_sizes; (void)n_in; (void)out_size; (void)ws_size;
    const float* vf = (const float*)d_in[0];
    const int* edges = (const int*)d_in[1];
    const float* w = (const float*)d_in[2];
    const float* W1 = (const float*)d_in[3];
    const float* b1 = (const float*)d_in[4];
    const float* W2 = (const float*)d_in[5];
    const float* b2 = (const float*)d_in[6];
    const float* W3 = (const float*)d_in[7];
    const float* b3 = (const float*)d_in[8];
    const float* W4 = (const float*)d_in[9];
    const float* b4 = (const float*)d_in[10];
    const float* Wl = (const float*)d_in[11];
    const float* bl = (const float*)d_in[12];
    float* out = (float*)d_out;

    const int* src = edges;
    const int* dst = edges + EE;

    // workspace: every region 256B-aligned, no aliasing
    char* base = (char*)d_ws;
    size_t off = 0;
    unsigned long long* packed = (unsigned long long*)(base + off);
    off = alignup(off + sizeof(unsigned long long) * NN);
    float* dinv = (float*)(base + off);   off = alignup(off + sizeof(float) * NN);
    int* cnt = (int*)(base + off);        off = alignup(off + sizeof(int) * NN);
    int* row_ptr = (int*)(base + off);    off = alignup(off + sizeof(int) * (NN + 1));
    int* cursor = (int*)(base + off);     off = alignup(off + sizeof(int) * NN);
    int* tmp = (int*)(base + off);        off = alignup(off + sizeof(int) * NN);
    int* partials = (int*)(base + off);   off = alignup(off + sizeof(int) * NBLK);
    int2* epack = (int2*)(base + off);    off = alignup(off + sizeof(int2) * EE);
    float* acc = (float*)(base + off);    off = alignup(off + sizeof(float) * (size_t)NN * HH);
    float* acc6 = (float*)(base + off);   off = alignup(off + sizeof(float) * (size_t)NN * FINN);
    __half* xh = (__half*)(base + off);   off = alignup(off + sizeof(__half) * (size_t)NN * HH);

    // degree + CSR build
    k_init<<<cdiv(NN, 256), 256, 0, stream>>>(packed);
    k_count<<<cdiv(EE, 256), 256, 0, stream>>>(dst, w, packed);
    k_post<<<cdiv(NN, 256), 256, 0, stream>>>(packed, dinv, cnt);
    k_scan1<<<NBLK, 256, 0, stream>>>(cnt, tmp, partials);
    k_scan2<<<1, 512, 0, stream>>>(partials);
    k_scan3<<<NBLK, 256, 0, stream>>>(tmp, partials, cnt, row_ptr, cursor);
    k_fill<<<cdiv(EE, 256), 256, 0, stream>>>(src, dst, w, dinv, cursor, epack);

    // layer 1: gather(6, fp32 vf) -> gemm+sigmoid -> fp16 xh
    k_gather6<<<cdiv(NN, 256), 256, 0, stream>>>(vf, dinv, row_ptr, epack, acc6);
    k_gemm_sig<FINN><<<cdiv(NN * 64, 256), 256, 0, stream>>>(acc6, W1, b1, xh);

    // layers 2..4: gather(64, fp16) -> fp32 acc -> gemm+sigmoid -> fp16 xh
    const float* Ws[3] = {W2, W3, W4};
    const float* bs[3] = {b2, b3, b4};
    for (int l = 0; l < 3; ++l) {
        k_gather64h<<<cdiv(NN, 4), 256, 0, stream>>>(xh, dinv, row_ptr, epack, acc);
        k_gemm_sig<HH><<<cdiv(NN * 64, 256), 256, 0, stream>>>(acc, Ws[l], bs[l], xh);
    }

    // head
    k_head<<<cdiv(NGNB * FOUT, 256), 256, 0, stream>>>(xh, Wl, bl, out);
}

// Round 5
// 977.989 us; speedup vs baseline: 3.5789x; 1.1902x over previous
//
#include <hip/hip_runtime.h>
#include <hip/hip_fp16.h>

#define NN 100000
#define EE 3200000
#define HH 64
#define FINN 6
#define FOUT 5
#define NGNB 50000
#define NBUK 391   // buckets of 256 nodes: bucket = dst >> 8
#define NBH 64     // blocks for hist/scatter passes

static inline int cdiv(int a, int b) { return (a + b - 1) / b; }
static inline size_t alignup(size_t x) { return (x + 255) & ~(size_t)255; }

// Pass A: per-block bucket histogram (LDS), write blockhist[block][NBUK]
__global__ __launch_bounds__(1024) void k_histA(const int* __restrict__ dst,
                                                int* __restrict__ blockhist) {
    __shared__ int hist[NBUK];
    int t = threadIdx.x;
    if (t < NBUK) hist[t] = 0;
    __syncthreads();
    for (int e = blockIdx.x * 1024 + t; e < EE; e += NBH * 1024)
        atomicAdd(&hist[dst[e] >> 8], 1);
    __syncthreads();
    if (t < NBUK) blockhist[blockIdx.x * NBUK + t] = hist[t];
}

// Pass B: turn blockhist into per-(block,bucket) bases; bucket_ptr = bucket starts
__global__ void k_scanB(int* __restrict__ blockhist, int* __restrict__ bucket_ptr) {
    __shared__ int sh[512];
    int t = threadIdx.x;
    int total = 0;
    if (t < NBUK)
        for (int b = 0; b < NBH; ++b) total += blockhist[b * NBUK + t];
    sh[t] = (t < NBUK) ? total : 0;
    __syncthreads();
    for (int off = 1; off < 512; off <<= 1) {
        int a = (t >= off) ? sh[t - off] : 0;
        __syncthreads();
        sh[t] += a;
        __syncthreads();
    }
    if (t < NBUK) {
        int base = sh[t] - total;  // exclusive
        bucket_ptr[t] = base;
        if (t == 0) bucket_ptr[NBUK] = EE;
        int run = base;
        for (int b = 0; b < NBH; ++b) {
            int c = blockhist[b * NBUK + t];
            blockhist[b * NBUK + t] = run;
            run += c;
        }
    }
}

// Pass C: scatter edges into bucket-grouped ebuk = {(dl<<17)|src, w}
__global__ __launch_bounds__(1024) void k_scatC(const int* __restrict__ src,
                                                const int* __restrict__ dst,
                                                const float* __restrict__ w,
                                                const int* __restrict__ blockhist,
                                                int2* __restrict__ ebuk) {
    __shared__ int cur[NBUK];
    int t = threadIdx.x;
    if (t < NBUK) cur[t] = blockhist[blockIdx.x * NBUK + t];
    __syncthreads();
    for (int e = blockIdx.x * 1024 + t; e < EE; e += NBH * 1024) {
        int d = dst[e];
        int k = d >> 8, dl = d & 255;
        int pos = atomicAdd(&cur[k], 1);
        int2 p;
        p.x = (dl << 17) | src[e];
        p.y = __float_as_int(w[e]);
        ebuk[pos] = p;
    }
}

// Pass D: per-bucket — LDS per-node count + weighted degree, scan, CSR scatter.
// Outputs: row_ptr, dinv, epack = {src, w}
__global__ __launch_bounds__(1024) void k_csrD(const int2* __restrict__ ebuk,
                                               const int* __restrict__ bucket_ptr,
                                               int* __restrict__ row_ptr,
                                               float* __restrict__ dinv,
                                               int2* __restrict__ epack) {
    __shared__ int cnt[256];
    __shared__ float wdeg[256];
    __shared__ int sh[256];
    __shared__ int cursor[256];
    int t = threadIdx.x;
    int k = blockIdx.x;
    if (t < 256) { cnt[t] = 0; wdeg[t] = 1.0f; }  // 1.0 = self-loop weight
    __syncthreads();
    int r0 = bucket_ptr[k], r1 = bucket_ptr[k + 1];
    for (int e = r0 + t; e < r1; e += 1024) {
        int2 p = ebuk[e];
        int dl = (p.x >> 17) & 255;
        atomicAdd(&cnt[dl], 1);
        atomicAdd(&wdeg[dl], __int_as_float(p.y));
    }
    __syncthreads();
    int c = 0;
    if (t < 256) { c = cnt[t]; sh[t] = c; }
    __syncthreads();
    for (int off = 1; off < 256; off <<= 1) {
        int a = (t < 256 && t >= off) ? sh[t - off] : 0;
        __syncthreads();
        if (t < 256) sh[t] += a;
        __syncthreads();
    }
    if (t < 256) {
        int gstart = r0 + sh[t] - c;  // exclusive within bucket + bucket base
        cursor[t] = gstart;
        int node = k * 256 + t;
        if (node < NN) {
            row_ptr[node] = gstart;
            dinv[node] = rsqrtf(wdeg[t]);
            if (node == NN - 1) row_ptr[NN] = EE;
        }
    }
    __syncthreads();
    for (int e = r0 + t; e < r1; e += 1024) {
        int2 p = ebuk[e];
        int dl = (p.x >> 17) & 255;
        int pos = atomicAdd(&cursor[dl], 1);
        int2 q;
        q.x = p.x & 0x1FFFF;
        q.y = p.y;
        epack[pos] = q;
    }
}

// vfs[i,f] = vf[i,f] * dinv[i]
__global__ void k_vfs(const float* __restrict__ vf, const float* __restrict__ dinv,
                      float* __restrict__ vfs) {
    int i = blockIdx.x * 256 + threadIdx.x;
    if (i >= NN) return;
    float di = dinv[i];
#pragma unroll
    for (int f = 0; f < FINN; ++f) vfs[i * FINN + f] = vf[i * FINN + f] * di;
}

// layer-1 aggregation: acc6[i] = dinv[i] * (vfs[i] + sum w * vfs[s])
__global__ void k_gather6(const float* __restrict__ vfs, const float* __restrict__ dinv,
                          const int* __restrict__ rp, const int2* __restrict__ epack,
                          float* __restrict__ acc6) {
    int i = blockIdx.x * 256 + threadIdx.x;
    if (i >= NN) return;
    float av[FINN];
#pragma unroll
    for (int f = 0; f < FINN; ++f) av[f] = vfs[i * FINN + f];
    int e1 = rp[i + 1];
    for (int e = rp[i]; e < e1; ++e) {
        int2 p = epack[e];
        float wn = __int_as_float(p.y);
#pragma unroll
        for (int f = 0; f < FINN; ++f) av[f] += vfs[p.x * FINN + f] * wn;
    }
    float di = dinv[i];
#pragma unroll
    for (int f = 0; f < FINN; ++f) acc6[i * FINN + f] = av[f] * di;
}

// 64-dim aggregation from fp16 y: acc[i] = dinv[i] * (y[i] + sum w * y[s])
// wave per node; lanes 0-31 even edges, 32-63 odd edges; shfl-combine.
__global__ __launch_bounds__(256) void k_gather64h(
    const __half* __restrict__ yh, const float* __restrict__ dinv,
    const int* __restrict__ rp, const int2* __restrict__ epack,
    float* __restrict__ acc) {
    int wv = threadIdx.x >> 6, lane = threadIdx.x & 63;
    int i = blockIdx.x * 4 + wv;
    if (i >= NN) return;
    int hf = lane >> 5, fp = lane & 31;
    float2 a = make_float2(0.0f, 0.0f);
    if (hf == 0) {  // self-loop term: y[i] (coefficient 1)
        float2 sv = __half22float2(((const __half2*)(yh + (size_t)i * HH))[fp]);
        a.x = sv.x;
        a.y = sv.y;
    }
    int e0 = rp[i], e1 = rp[i + 1];
    for (int e = e0 + hf; e < e1; e += 2) {
        int2 p = epack[e];
        float wn = __int_as_float(p.y);
        float2 v = __half22float2(((const __half2*)(yh + (size_t)p.x * HH))[fp]);
        a.x += v.x * wn;
        a.y += v.y * wn;
    }
    a.x += __shfl(a.x, lane ^ 32, 64);
    a.y += __shfl(a.y, lane ^ 32, 64);
    if (hf == 0) {
        float di = dinv[i];
        float2 o;
        o.x = a.x * di;
        o.y = a.y * di;
        ((float2*)(acc + (size_t)i * HH))[fp] = o;
    }
}

// out[i,:] = sigmoid(acc[i,:FI] @ W + b); SCALED: multiply by dinv[i] (store y)
template <int FI, bool SCALED>
__global__ void k_gemm_sig(const float* __restrict__ x, const float* __restrict__ W,
                           const float* __restrict__ b, const float* __restrict__ dinv,
                           __half* __restrict__ out) {
    __shared__ float Wl[FI * 64];
    __shared__ float bl[64];
    for (int t = threadIdx.x; t < FI * 64; t += 256) Wl[t] = W[t];
    if (threadIdx.x < 64) bl[threadIdx.x] = b[threadIdx.x];
    __syncthreads();
    int wave = (blockIdx.x * 256 + threadIdx.x) >> 6;
    int lane = threadIdx.x & 63;
    if (wave >= NN) return;
    const float* xr = x + (size_t)wave * FI;
    float s = bl[lane];
#pragma unroll
    for (int f = 0; f < FI; ++f) s += xr[f] * Wl[f * 64 + lane];
    float sig = 1.0f / (1.0f + __expf(-s));
    if (SCALED) sig *= dinv[wave];
    out[(size_t)wave * HH + lane] = __float2half(sig);
}

// head: out[i,j] = x[i,:] @ Wl[:,j] + bl[j]  (x = unscaled sigmoid fp16)
__global__ void k_head(const __half* __restrict__ xh, const float* __restrict__ Wl,
                       const float* __restrict__ bl, float* __restrict__ out) {
    int tid = blockIdx.x * 256 + threadIdx.x;
    if (tid >= NGNB * FOUT) return;
    int i = tid / FOUT;
    int j = tid - i * FOUT;
    const __half* xr = xh + (size_t)i * HH;
    float s = bl[j];
#pragma unroll
    for (int f = 0; f < HH; ++f) s += __half2float(xr[f]) * Wl[f * FOUT + j];
    out[tid] = s;
}

extern "C" void kernel_launch(void* const* d_in, const int* in_sizes, int n_in,
                              void* d_out, int out_size, void* d_ws, size_t ws_size,
                              hipStream_t stream) {
    (void)in_sizes; (void)n_in; (void)out_size; (void)ws_size;
    const float* vf = (const float*)d_in[0];
    const int* edges = (const int*)d_in[1];
    const float* w = (const float*)d_in[2];
    const float* W1 = (const float*)d_in[3];
    const float* b1 = (const float*)d_in[4];
    const float* W2 = (const float*)d_in[5];
    const float* b2 = (const float*)d_in[6];
    const float* W3 = (const float*)d_in[7];
    const float* b3 = (const float*)d_in[8];
    const float* W4 = (const float*)d_in[9];
    const float* b4 = (const float*)d_in[10];
    const float* Wl = (const float*)d_in[11];
    const float* bl = (const float*)d_in[12];
    float* out = (float*)d_out;

    const int* src = edges;
    const int* dst = edges + EE;

    // workspace: 256B-aligned regions. acc aliases ebuk (ebuk dead after k_csrD).
    char* base = (char*)d_ws;
    size_t off = 0;
    float* dinv = (float*)(base + off);      off = alignup(off + sizeof(float) * NN);
    int* row_ptr = (int*)(base + off);       off = alignup(off + sizeof(int) * (NN + 1));
    int* bucket_ptr = (int*)(base + off);    off = alignup(off + sizeof(int) * (NBUK + 1));
    int* blockhist = (int*)(base + off);     off = alignup(off + sizeof(int) * NBH * NBUK);
    int2* ebuk = (int2*)(base + off);        off = alignup(off + sizeof(int2) * EE);
    float* acc = (float*)ebuk;               // alias: N*64 fp32 == E int2 == 25.6 MB
    int2* epack = (int2*)(base + off);       off = alignup(off + sizeof(int2) * EE);
    float* acc6 = (float*)(base + off);      off = alignup(off + sizeof(float) * (size_t)NN * FINN);
    float* vfs = (float*)(base + off);       off = alignup(off + sizeof(float) * (size_t)NN * FINN);
    __half* yh = (__half*)(base + off);      off = alignup(off + sizeof(__half) * (size_t)NN * HH);

    // CSR build via two-level bucket sort (no global atomics)
    k_histA<<<NBH, 1024, 0, stream>>>(dst, blockhist);
    k_scanB<<<1, 512, 0, stream>>>(blockhist, bucket_ptr);
    k_scatC<<<NBH, 1024, 0, stream>>>(src, dst, w, blockhist, ebuk);
    k_csrD<<<NBUK, 1024, 0, stream>>>(ebuk, bucket_ptr, row_ptr, dinv, epack);

    // scaled input features
    k_vfs<<<cdiv(NN, 256), 256, 0, stream>>>(vf, dinv, vfs);

    // layer 1: gather(6) -> gemm+sigmoid (scaled -> y)
    k_gather6<<<cdiv(NN, 256), 256, 0, stream>>>(vfs, dinv, row_ptr, epack, acc6);
    k_gemm_sig<FINN, true><<<cdiv(NN * 64, 256), 256, 0, stream>>>(acc6, W1, b1, dinv, yh);

    // layers 2,3: gather(64) -> gemm+sigmoid (scaled -> y)
    k_gather64h<<<cdiv(NN, 4), 256, 0, stream>>>(yh, dinv, row_ptr, epack, acc);
    k_gemm_sig<HH, true><<<cdiv(NN * 64, 256), 256, 0, stream>>>(acc, W2, b2, dinv, yh);
    k_gather64h<<<cdiv(NN, 4), 256, 0, stream>>>(yh, dinv, row_ptr, epack, acc);
    k_gemm_sig<HH, true><<<cdiv(NN * 64, 256), 256, 0, stream>>>(acc, W3, b3, dinv, yh);

    // layer 4: gather(64) -> gemm+sigmoid (unscaled, feeds head)
    k_gather64h<<<cdiv(NN, 4), 256, 0, stream>>>(yh, dinv, row_ptr, epack, acc);
    k_gemm_sig<HH, false><<<cdiv(NN * 64, 256), 256, 0, stream>>>(acc, W4, b4, dinv, yh);

    // head
    k_head<<<cdiv(NGNB * FOUT, 256), 256, 0, stream>>>(yh, Wl, bl, out);
}

// Round 6
// 763.379 us; speedup vs baseline: 4.5851x; 1.2811x over previous
//
#include <hip/hip_runtime.h>
#include <hip/hip_fp16.h>

#define NN 100000
#define EE 3200000
#define HH 64
#define FINN 6
#define FOUT 5
#define NGNB 50000
#define NBUK 391   // buckets of 256 nodes: bucket = dst >> 8
#define NBH 64     // blocks for hist/scatter passes

static inline int cdiv(int a, int b) { return (a + b - 1) / b; }
static inline size_t alignup(size_t x) { return (x + 255) & ~(size_t)255; }

// Pass A: per-block bucket histogram (LDS), write blockhist[block][NBUK]
__global__ __launch_bounds__(1024) void k_histA(const int* __restrict__ dst,
                                                int* __restrict__ blockhist) {
    __shared__ int hist[NBUK];
    int t = threadIdx.x;
    if (t < NBUK) hist[t] = 0;
    __syncthreads();
    for (int e = blockIdx.x * 1024 + t; e < EE; e += NBH * 1024)
        atomicAdd(&hist[dst[e] >> 8], 1);
    __syncthreads();
    if (t < NBUK) blockhist[blockIdx.x * NBUK + t] = hist[t];
}

// Pass B: turn blockhist into per-(block,bucket) bases; bucket_ptr = bucket starts
__global__ void k_scanB(int* __restrict__ blockhist, int* __restrict__ bucket_ptr) {
    __shared__ int sh[512];
    int t = threadIdx.x;
    int total = 0;
    if (t < NBUK)
        for (int b = 0; b < NBH; ++b) total += blockhist[b * NBUK + t];
    sh[t] = (t < NBUK) ? total : 0;
    __syncthreads();
    for (int off = 1; off < 512; off <<= 1) {
        int a = (t >= off) ? sh[t - off] : 0;
        __syncthreads();
        sh[t] += a;
        __syncthreads();
    }
    if (t < NBUK) {
        int base = sh[t] - total;  // exclusive
        bucket_ptr[t] = base;
        if (t == 0) bucket_ptr[NBUK] = EE;
        int run = base;
        for (int b = 0; b < NBH; ++b) {
            int c = blockhist[b * NBUK + t];
            blockhist[b * NBUK + t] = run;
            run += c;
        }
    }
}

// Pass C: scatter edges into bucket-grouped ebuk = {(dl<<17)|src, w}
__global__ __launch_bounds__(1024) void k_scatC(const int* __restrict__ src,
                                                const int* __restrict__ dst,
                                                const float* __restrict__ w,
                                                const int* __restrict__ blockhist,
                                                int2* __restrict__ ebuk) {
    __shared__ int cur[NBUK];
    int t = threadIdx.x;
    if (t < NBUK) cur[t] = blockhist[blockIdx.x * NBUK + t];
    __syncthreads();
    for (int e = blockIdx.x * 1024 + t; e < EE; e += NBH * 1024) {
        int d = dst[e];
        int k = d >> 8, dl = d & 255;
        int pos = atomicAdd(&cur[k], 1);
        int2 p;
        p.x = (dl << 17) | src[e];
        p.y = __float_as_int(w[e]);
        ebuk[pos] = p;
    }
}

// Pass D: per-bucket — LDS per-node count + weighted degree, scan, CSR scatter.
__global__ __launch_bounds__(1024) void k_csrD(const int2* __restrict__ ebuk,
                                               const int* __restrict__ bucket_ptr,
                                               int* __restrict__ row_ptr,
                                               float* __restrict__ dinv,
                                               int2* __restrict__ epack) {
    __shared__ int cnt[256];
    __shared__ float wdeg[256];
    __shared__ int sh[256];
    __shared__ int cursor[256];
    int t = threadIdx.x;
    int k = blockIdx.x;
    if (t < 256) { cnt[t] = 0; wdeg[t] = 1.0f; }  // 1.0 = self-loop weight
    __syncthreads();
    int r0 = bucket_ptr[k], r1 = bucket_ptr[k + 1];
    for (int e = r0 + t; e < r1; e += 1024) {
        int2 p = ebuk[e];
        int dl = (p.x >> 17) & 255;
        atomicAdd(&cnt[dl], 1);
        atomicAdd(&wdeg[dl], __int_as_float(p.y));
    }
    __syncthreads();
    int c = 0;
    if (t < 256) { c = cnt[t]; sh[t] = c; }
    __syncthreads();
    for (int off = 1; off < 256; off <<= 1) {
        int a = (t < 256 && t >= off) ? sh[t - off] : 0;
        __syncthreads();
        if (t < 256) sh[t] += a;
        __syncthreads();
    }
    if (t < 256) {
        int gstart = r0 + sh[t] - c;
        cursor[t] = gstart;
        int node = k * 256 + t;
        if (node < NN) {
            row_ptr[node] = gstart;
            dinv[node] = rsqrtf(wdeg[t]);
            if (node == NN - 1) row_ptr[NN] = EE;
        }
    }
    __syncthreads();
    for (int e = r0 + t; e < r1; e += 1024) {
        int2 p = ebuk[e];
        int dl = (p.x >> 17) & 255;
        int pos = atomicAdd(&cursor[dl], 1);
        int2 q;
        q.x = p.x & 0x1FFFF;
        q.y = p.y;
        epack[pos] = q;
    }
}

// vfs[i,f] = vf[i,f] * dinv[i]
__global__ void k_vfs(const float* __restrict__ vf, const float* __restrict__ dinv,
                      float* __restrict__ vfs) {
    int i = blockIdx.x * 256 + threadIdx.x;
    if (i >= NN) return;
    float di = dinv[i];
#pragma unroll
    for (int f = 0; f < FINN; ++f) vfs[i * FINN + f] = vf[i * FINN + f] * di;
}

// layer-1 aggregation: acc6[i] = dinv[i] * (vfs[i] + sum w * vfs[s])
__global__ void k_gather6(const float* __restrict__ vfs, const float* __restrict__ dinv,
                          const int* __restrict__ rp, const int2* __restrict__ epack,
                          float* __restrict__ acc6) {
    int i = blockIdx.x * 256 + threadIdx.x;
    if (i >= NN) return;
    float av[FINN];
#pragma unroll
    for (int f = 0; f < FINN; ++f) av[f] = vfs[i * FINN + f];
    int e1 = rp[i + 1];
    for (int e = rp[i]; e < e1; ++e) {
        int2 p = epack[e];
        float wn = __int_as_float(p.y);
#pragma unroll
        for (int f = 0; f < FINN; ++f) av[f] += vfs[p.x * FINN + f] * wn;
    }
    float di = dinv[i];
#pragma unroll
    for (int f = 0; f < FINN; ++f) acc6[i * FINN + f] = av[f] * di;
}

// Fused 64-dim layer: wave per node, register-staged edges (src/w via shfl),
// then in-LDS 64->64 GEMM + bias + sigmoid. Reads yin, writes yout (ping-pong).
template <bool SCALED>
__global__ __launch_bounds__(256) void k_layer64f(
    const __half* __restrict__ yin, const float* __restrict__ dinv,
    const int* __restrict__ rp, const int2* __restrict__ epack,
    const float* __restrict__ W, const float* __restrict__ b,
    __half* __restrict__ yout) {
    __shared__ float Wsh[HH * HH];   // 16 KB
    __shared__ float bsh[HH];
    __shared__ float aggsh[4 * HH];
    for (int t = threadIdx.x; t < HH * HH; t += 256) Wsh[t] = W[t];
    if (threadIdx.x < HH) bsh[threadIdx.x] = b[threadIdx.x];

    int wv = threadIdx.x >> 6, lane = threadIdx.x & 63;
    int i = blockIdx.x * 4 + wv;
    int hf = lane >> 5, fp = lane & 31;
    float2 a = make_float2(0.0f, 0.0f);
    float di = 0.0f;
    if (i < NN) {
        di = dinv[i];
        if (hf == 0) {  // self-loop term: y[i] (coefficient 1)
            float2 sv = __half22float2(((const __half2*)(yin + (size_t)i * HH))[fp]);
            a.x = sv.x;
            a.y = sv.y;
        }
        int e0 = rp[i], e1 = rp[i + 1];
        for (int base = e0; base < e1; base += 64) {
            int n = e1 - base;
            if (n > 64) n = 64;
            int2 p = make_int2(0, 0);
            if (lane < n) p = epack[base + lane];  // coalesced 512B/wave
            for (int j = 0; j < n; j += 2) {
                int eidx = j + hf;
                int sj = __shfl(p.x, eidx, 64);
                float wj = __int_as_float(__shfl(p.y, eidx, 64));
                if (eidx < n) {
                    float2 v = __half22float2(((const __half2*)(yin + (size_t)sj * HH))[fp]);
                    a.x += v.x * wj;
                    a.y += v.y * wj;
                }
            }
        }
        a.x += __shfl(a.x, lane ^ 32, 64);
        a.y += __shfl(a.y, lane ^ 32, 64);
    }
    __syncthreads();  // Wsh/bsh staged
    if (i < NN && hf == 0) {
        float2 o;
        o.x = a.x * di;
        o.y = a.y * di;
        ((float2*)&aggsh[wv * HH])[fp] = o;
    }
    __syncthreads();
    if (i >= NN) return;
    float o = bsh[lane];
    const float4* a4 = (const float4*)&aggsh[wv * HH];
#pragma unroll
    for (int f0 = 0; f0 < HH; f0 += 4) {
        float4 av = a4[f0 >> 2];  // broadcast read
        o += av.x * Wsh[(f0 + 0) * HH + lane];
        o += av.y * Wsh[(f0 + 1) * HH + lane];
        o += av.z * Wsh[(f0 + 2) * HH + lane];
        o += av.w * Wsh[(f0 + 3) * HH + lane];
    }
    float sig = 1.0f / (1.0f + __expf(-o));
    if (SCALED) sig *= di;
    yout[(size_t)i * HH + lane] = __float2half(sig);
}

// out[i,:] = sigmoid(acc6[i,:FI] @ W + b) * dinv  (layer 1 only)
template <int FI>
__global__ void k_gemm_sig(const float* __restrict__ x, const float* __restrict__ W,
                           const float* __restrict__ b, const float* __restrict__ dinv,
                           __half* __restrict__ out) {
    __shared__ float Wl[FI * 64];
    __shared__ float bl[64];
    for (int t = threadIdx.x; t < FI * 64; t += 256) Wl[t] = W[t];
    if (threadIdx.x < 64) bl[threadIdx.x] = b[threadIdx.x];
    __syncthreads();
    int wave = (blockIdx.x * 256 + threadIdx.x) >> 6;
    int lane = threadIdx.x & 63;
    if (wave >= NN) return;
    const float* xr = x + (size_t)wave * FI;
    float s = bl[lane];
#pragma unroll
    for (int f = 0; f < FI; ++f) s += xr[f] * Wl[f * 64 + lane];
    float sig = 1.0f / (1.0f + __expf(-s));
    sig *= dinv[wave];
    out[(size_t)wave * HH + lane] = __float2half(sig);
}

// head: out[i,j] = x[i,:] @ Wl[:,j] + bl[j]  (x = unscaled sigmoid fp16)
__global__ void k_head(const __half* __restrict__ xh, const float* __restrict__ Wl,
                       const float* __restrict__ bl, float* __restrict__ out) {
    int tid = blockIdx.x * 256 + threadIdx.x;
    if (tid >= NGNB * FOUT) return;
    int i = tid / FOUT;
    int j = tid - i * FOUT;
    const __half* xr = xh + (size_t)i * HH;
    float s = bl[j];
#pragma unroll
    for (int f = 0; f < HH; ++f) s += __half2float(xr[f]) * Wl[f * FOUT + j];
    out[tid] = s;
}

extern "C" void kernel_launch(void* const* d_in, const int* in_sizes, int n_in,
                              void* d_out, int out_size, void* d_ws, size_t ws_size,
                              hipStream_t stream) {
    (void)in_sizes; (void)n_in; (void)out_size; (void)ws_size;
    const float* vf = (const float*)d_in[0];
    const int* edges = (const int*)d_in[1];
    const float* w = (const float*)d_in[2];
    const float* W1 = (const float*)d_in[3];
    const float* b1 = (const float*)d_in[4];
    const float* W2 = (const float*)d_in[5];
    const float* b2 = (const float*)d_in[6];
    const float* W3 = (const float*)d_in[7];
    const float* b3 = (const float*)d_in[8];
    const float* W4 = (const float*)d_in[9];
    const float* b4 = (const float*)d_in[10];
    const float* Wl = (const float*)d_in[11];
    const float* bl = (const float*)d_in[12];
    float* out = (float*)d_out;

    const int* src = edges;
    const int* dst = edges + EE;

    // workspace: 256B-aligned regions
    char* base = (char*)d_ws;
    size_t off = 0;
    float* dinv = (float*)(base + off);      off = alignup(off + sizeof(float) * NN);
    int* row_ptr = (int*)(base + off);       off = alignup(off + sizeof(int) * (NN + 1));
    int* bucket_ptr = (int*)(base + off);    off = alignup(off + sizeof(int) * (NBUK + 1));
    int* blockhist = (int*)(base + off);     off = alignup(off + sizeof(int) * NBH * NBUK);
    int2* ebuk = (int2*)(base + off);        off = alignup(off + sizeof(int2) * EE);
    int2* epack = (int2*)(base + off);       off = alignup(off + sizeof(int2) * EE);
    float* acc6 = (float*)(base + off);      off = alignup(off + sizeof(float) * (size_t)NN * FINN);
    float* vfs = (float*)(base + off);       off = alignup(off + sizeof(float) * (size_t)NN * FINN);
    __half* ya = (__half*)(base + off);      off = alignup(off + sizeof(__half) * (size_t)NN * HH);
    __half* yb = (__half*)(base + off);      off = alignup(off + sizeof(__half) * (size_t)NN * HH);

    // CSR build via two-level bucket sort (no global atomics)
    k_histA<<<NBH, 1024, 0, stream>>>(dst, blockhist);
    k_scanB<<<1, 512, 0, stream>>>(blockhist, bucket_ptr);
    k_scatC<<<NBH, 1024, 0, stream>>>(src, dst, w, blockhist, ebuk);
    k_csrD<<<NBUK, 1024, 0, stream>>>(ebuk, bucket_ptr, row_ptr, dinv, epack);

    // scaled input features
    k_vfs<<<cdiv(NN, 256), 256, 0, stream>>>(vf, dinv, vfs);

    // layer 1: gather(6) -> gemm+sigmoid (scaled -> y)
    k_gather6<<<cdiv(NN, 256), 256, 0, stream>>>(vfs, dinv, row_ptr, epack, acc6);
    k_gemm_sig<FINN><<<cdiv(NN * 64, 256), 256, 0, stream>>>(acc6, W1, b1, dinv, ya);

    // layers 2,3 fused (scaled -> y), ping-pong; layer 4 fused (unscaled)
    k_layer64f<true><<<cdiv(NN, 4), 256, 0, stream>>>(ya, dinv, row_ptr, epack, W2, b2, yb);
    k_layer64f<true><<<cdiv(NN, 4), 256, 0, stream>>>(yb, dinv, row_ptr, epack, W3, b3, ya);
    k_layer64f<false><<<cdiv(NN, 4), 256, 0, stream>>>(ya, dinv, row_ptr, epack, W4, b4, yb);

    // head
    k_head<<<cdiv(NGNB * FOUT, 256), 256, 0, stream>>>(yb, Wl, bl, out);
}

// Round 7
// 576.354 us; speedup vs baseline: 6.0730x; 1.3245x over previous
//
#include <hip/hip_runtime.h>
#include <hip/hip_fp16.h>

#define NN 100000
#define EE 3200000
#define HH 64
#define FINN 6
#define FOUT 5
#define NGNB 50000
#define NBUK 391   // buckets of 256 nodes: bucket = dst >> 8
#define NBH 64     // blocks for hist/scatter passes

static inline int cdiv(int a, int b) { return (a + b - 1) / b; }
static inline size_t alignup(size_t x) { return (x + 255) & ~(size_t)255; }

// Pass A: per-block bucket histogram (LDS), write blockhist[block][NBUK]
__global__ __launch_bounds__(1024) void k_histA(const int* __restrict__ dst,
                                                int* __restrict__ blockhist) {
    __shared__ int hist[NBUK];
    int t = threadIdx.x;
    if (t < NBUK) hist[t] = 0;
    __syncthreads();
    for (int e = blockIdx.x * 1024 + t; e < EE; e += NBH * 1024)
        atomicAdd(&hist[dst[e] >> 8], 1);
    __syncthreads();
    if (t < NBUK) blockhist[blockIdx.x * NBUK + t] = hist[t];
}

// Pass B: turn blockhist into per-(block,bucket) bases; bucket_ptr = bucket starts
__global__ void k_scanB(int* __restrict__ blockhist, int* __restrict__ bucket_ptr) {
    __shared__ int sh[512];
    int t = threadIdx.x;
    int total = 0;
    if (t < NBUK)
        for (int b = 0; b < NBH; ++b) total += blockhist[b * NBUK + t];
    sh[t] = (t < NBUK) ? total : 0;
    __syncthreads();
    for (int off = 1; off < 512; off <<= 1) {
        int a = (t >= off) ? sh[t - off] : 0;
        __syncthreads();
        sh[t] += a;
        __syncthreads();
    }
    if (t < NBUK) {
        int base = sh[t] - total;  // exclusive
        bucket_ptr[t] = base;
        if (t == 0) bucket_ptr[NBUK] = EE;
        int run = base;
        for (int b = 0; b < NBH; ++b) {
            int c = blockhist[b * NBUK + t];
            blockhist[b * NBUK + t] = run;
            run += c;
        }
    }
}

// Pass C: scatter edges into bucket-grouped ebuk = {(dl<<17)|src, w}
__global__ __launch_bounds__(1024) void k_scatC(const int* __restrict__ src,
                                                const int* __restrict__ dst,
                                                const float* __restrict__ w,
                                                const int* __restrict__ blockhist,
                                                int2* __restrict__ ebuk) {
    __shared__ int cur[NBUK];
    int t = threadIdx.x;
    if (t < NBUK) cur[t] = blockhist[blockIdx.x * NBUK + t];
    __syncthreads();
    for (int e = blockIdx.x * 1024 + t; e < EE; e += NBH * 1024) {
        int d = dst[e];
        int k = d >> 8, dl = d & 255;
        int pos = atomicAdd(&cur[k], 1);
        int2 p;
        p.x = (dl << 17) | src[e];
        p.y = __float_as_int(w[e]);
        ebuk[pos] = p;
    }
}

// Pass D: per-bucket — LDS per-node count + weighted degree, scan, CSR scatter.
__global__ __launch_bounds__(1024) void k_csrD(const int2* __restrict__ ebuk,
                                               const int* __restrict__ bucket_ptr,
                                               int* __restrict__ row_ptr,
                                               float* __restrict__ dinv,
                                               int2* __restrict__ epack) {
    __shared__ int cnt[256];
    __shared__ float wdeg[256];
    __shared__ int sh[256];
    __shared__ int cursor[256];
    int t = threadIdx.x;
    int k = blockIdx.x;
    if (t < 256) { cnt[t] = 0; wdeg[t] = 1.0f; }  // 1.0 = self-loop weight
    __syncthreads();
    int r0 = bucket_ptr[k], r1 = bucket_ptr[k + 1];
    for (int e = r0 + t; e < r1; e += 1024) {
        int2 p = ebuk[e];
        int dl = (p.x >> 17) & 255;
        atomicAdd(&cnt[dl], 1);
        atomicAdd(&wdeg[dl], __int_as_float(p.y));
    }
    __syncthreads();
    int c = 0;
    if (t < 256) { c = cnt[t]; sh[t] = c; }
    __syncthreads();
    for (int off = 1; off < 256; off <<= 1) {
        int a = (t < 256 && t >= off) ? sh[t - off] : 0;
        __syncthreads();
        if (t < 256) sh[t] += a;
        __syncthreads();
    }
    if (t < 256) {
        int gstart = r0 + sh[t] - c;
        cursor[t] = gstart;
        int node = k * 256 + t;
        if (node < NN) {
            row_ptr[node] = gstart;
            dinv[node] = rsqrtf(wdeg[t]);
            if (node == NN - 1) row_ptr[NN] = EE;
        }
    }
    __syncthreads();
    for (int e = r0 + t; e < r1; e += 1024) {
        int2 p = ebuk[e];
        int dl = (p.x >> 17) & 255;
        int pos = atomicAdd(&cursor[dl], 1);
        int2 q;
        q.x = p.x & 0x1FFFF;
        q.y = p.y;
        epack[pos] = q;
    }
}

// vfs[i,f] = vf[i,f] * dinv[i]
__global__ void k_vfs(const float* __restrict__ vf, const float* __restrict__ dinv,
                      float* __restrict__ vfs) {
    int i = blockIdx.x * 256 + threadIdx.x;
    if (i >= NN) return;
    float di = dinv[i];
#pragma unroll
    for (int f = 0; f < FINN; ++f) vfs[i * FINN + f] = vf[i * FINN + f] * di;
}

// layer-1 aggregation: acc6[i] = dinv[i] * (vfs[i] + sum w * vfs[s])
__global__ void k_gather6(const float* __restrict__ vfs, const float* __restrict__ dinv,
                          const int* __restrict__ rp, const int2* __restrict__ epack,
                          float* __restrict__ acc6) {
    int i = blockIdx.x * 256 + threadIdx.x;
    if (i >= NN) return;
    float av[FINN];
#pragma unroll
    for (int f = 0; f < FINN; ++f) av[f] = vfs[i * FINN + f];
    int e1 = rp[i + 1];
    for (int e = rp[i]; e < e1; ++e) {
        int2 p = epack[e];
        float wn = __int_as_float(p.y);
#pragma unroll
        for (int f = 0; f < FINN; ++f) av[f] += vfs[p.x * FINN + f] * wn;
    }
    float di = dinv[i];
#pragma unroll
    for (int f = 0; f < FINN; ++f) acc6[i * FINN + f] = av[f] * di;
}

// Fused 64-dim layer: wave per node, 8 nodes/block. Wave-uniform edge loop
// (readfirstlane bounds -> scalar/broadcast epack loads), full-row ushort
// gathers (lane = feature), then in-LDS 64->64 GEMM + bias + sigmoid.
// HEAD: compute only NGNB nodes, fuse the 64->5 head, write out directly.
template <bool HEAD>
__global__ __launch_bounds__(512) void k_layer64f(
    const __half* __restrict__ yin, const float* __restrict__ dinv,
    const int* __restrict__ rp, const int2* __restrict__ epack,
    const float* __restrict__ W, const float* __restrict__ b,
    __half* __restrict__ yout,
    const float* __restrict__ Wl, const float* __restrict__ bl,
    float* __restrict__ outp) {
    __shared__ float Wsh[HH * HH];   // 16 KB
    __shared__ float bsh[HH];
    __shared__ float aggsh[8 * HH];
    __shared__ float Wlsh[HH * FOUT];
    __shared__ float blsh[FOUT];
    for (int t = threadIdx.x; t < HH * HH; t += 512) Wsh[t] = W[t];
    if (threadIdx.x < HH) bsh[threadIdx.x] = b[threadIdx.x];
    if (HEAD) {
        for (int t = threadIdx.x; t < HH * FOUT; t += 512) Wlsh[t] = Wl[t];
        if (threadIdx.x < FOUT) blsh[threadIdx.x] = bl[threadIdx.x];
    }

    int wv = threadIdx.x >> 6, lane = threadIdx.x & 63;
    int i = blockIdx.x * 8 + wv;  // grids divide exactly: no partial blocks
    float di = dinv[i];
    float agg = __half2float(yin[(size_t)i * HH + lane]);  // self loop (coeff 1)
    int e0 = __builtin_amdgcn_readfirstlane(rp[i]);
    int e1 = __builtin_amdgcn_readfirstlane(rp[i + 1]);
    int e = e0;
    for (; e + 4 <= e1; e += 4) {  // 4 independent row loads in flight
        int2 p0 = epack[e];
        int2 p1 = epack[e + 1];
        int2 p2 = epack[e + 2];
        int2 p3 = epack[e + 3];
        float v0 = __half2float(yin[(size_t)p0.x * HH + lane]);
        float v1 = __half2float(yin[(size_t)p1.x * HH + lane]);
        float v2 = __half2float(yin[(size_t)p2.x * HH + lane]);
        float v3 = __half2float(yin[(size_t)p3.x * HH + lane]);
        agg += v0 * __int_as_float(p0.y);
        agg += v1 * __int_as_float(p1.y);
        agg += v2 * __int_as_float(p2.y);
        agg += v3 * __int_as_float(p3.y);
    }
    for (; e < e1; ++e) {
        int2 p = epack[e];
        agg += __half2float(yin[(size_t)p.x * HH + lane]) * __int_as_float(p.y);
    }
    __syncthreads();  // Wsh/bsh staged
    aggsh[wv * HH + lane] = agg * di;
    __syncthreads();
    float o = bsh[lane];
    const float4* a4 = (const float4*)&aggsh[wv * HH];
#pragma unroll
    for (int f0 = 0; f0 < HH; f0 += 4) {
        float4 av = a4[f0 >> 2];  // broadcast read
        o += av.x * Wsh[(f0 + 0) * HH + lane];
        o += av.y * Wsh[(f0 + 1) * HH + lane];
        o += av.z * Wsh[(f0 + 2) * HH + lane];
        o += av.w * Wsh[(f0 + 3) * HH + lane];
    }
    float sig = 1.0f / (1.0f + __expf(-o));
    if (!HEAD) {
        yout[(size_t)i * HH + lane] = __float2half(sig * di);  // scaled y
    } else {
        aggsh[wv * HH + lane] = sig;  // unscaled, own-wave slice only
        __syncthreads();
        if (lane < FOUT) {
            float s = blsh[lane];
            const float* ar = &aggsh[wv * HH];
#pragma unroll
            for (int f = 0; f < HH; ++f) s += ar[f] * Wlsh[f * FOUT + lane];
            outp[(size_t)i * FOUT + lane] = s;
        }
    }
}

// out[i,:] = sigmoid(acc6[i,:FI] @ W + b) * dinv  (layer 1 only)
template <int FI>
__global__ void k_gemm_sig(const float* __restrict__ x, const float* __restrict__ W,
                           const float* __restrict__ b, const float* __restrict__ dinv,
                           __half* __restrict__ out) {
    __shared__ float Wsl[FI * 64];
    __shared__ float bsl[64];
    for (int t = threadIdx.x; t < FI * 64; t += 256) Wsl[t] = W[t];
    if (threadIdx.x < 64) bsl[threadIdx.x] = b[threadIdx.x];
    __syncthreads();
    int wave = (blockIdx.x * 256 + threadIdx.x) >> 6;
    int lane = threadIdx.x & 63;
    if (wave >= NN) return;
    const float* xr = x + (size_t)wave * FI;
    float s = bsl[lane];
#pragma unroll
    for (int f = 0; f < FI; ++f) s += xr[f] * Wsl[f * 64 + lane];
    float sig = 1.0f / (1.0f + __expf(-s));
    sig *= dinv[wave];
    out[(size_t)wave * HH + lane] = __float2half(sig);
}

extern "C" void kernel_launch(void* const* d_in, const int* in_sizes, int n_in,
                              void* d_out, int out_size, void* d_ws, size_t ws_size,
                              hipStream_t stream) {
    (void)in_sizes; (void)n_in; (void)out_size; (void)ws_size;
    const float* vf = (const float*)d_in[0];
    const int* edges = (const int*)d_in[1];
    const float* w = (const float*)d_in[2];
    const float* W1 = (const float*)d_in[3];
    const float* b1 = (const float*)d_in[4];
    const float* W2 = (const float*)d_in[5];
    const float* b2 = (const float*)d_in[6];
    const float* W3 = (const float*)d_in[7];
    const float* b3 = (const float*)d_in[8];
    const float* W4 = (const float*)d_in[9];
    const float* b4 = (const float*)d_in[10];
    const float* Wl = (const float*)d_in[11];
    const float* bl = (const float*)d_in[12];
    float* out = (float*)d_out;

    const int* src = edges;
    const int* dst = edges + EE;

    // workspace: 256B-aligned regions
    char* base = (char*)d_ws;
    size_t off = 0;
    float* dinv = (float*)(base + off);      off = alignup(off + sizeof(float) * NN);
    int* row_ptr = (int*)(base + off);       off = alignup(off + sizeof(int) * (NN + 1));
    int* bucket_ptr = (int*)(base + off);    off = alignup(off + sizeof(int) * (NBUK + 1));
    int* blockhist = (int*)(base + off);     off = alignup(off + sizeof(int) * NBH * NBUK);
    int2* ebuk = (int2*)(base + off);        off = alignup(off + sizeof(int2) * EE);
    int2* epack = (int2*)(base + off);       off = alignup(off + sizeof(int2) * EE);
    float* acc6 = (float*)(base + off);      off = alignup(off + sizeof(float) * (size_t)NN * FINN);
    float* vfs = (float*)(base + off);       off = alignup(off + sizeof(float) * (size_t)NN * FINN);
    __half* ya = (__half*)(base + off);      off = alignup(off + sizeof(__half) * (size_t)NN * HH);
    __half* yb = (__half*)(base + off);      off = alignup(off + sizeof(__half) * (size_t)NN * HH);

    // CSR build via two-level bucket sort (no global atomics)
    k_histA<<<NBH, 1024, 0, stream>>>(dst, blockhist);
    k_scanB<<<1, 512, 0, stream>>>(blockhist, bucket_ptr);
    k_scatC<<<NBH, 1024, 0, stream>>>(src, dst, w, blockhist, ebuk);
    k_csrD<<<NBUK, 1024, 0, stream>>>(ebuk, bucket_ptr, row_ptr, dinv, epack);

    // scaled input features
    k_vfs<<<cdiv(NN, 256), 256, 0, stream>>>(vf, dinv, vfs);

    // layer 1: gather(6) -> gemm+sigmoid (scaled -> ya)
    k_gather6<<<cdiv(NN, 256), 256, 0, stream>>>(vfs, dinv, row_ptr, epack, acc6);
    k_gemm_sig<FINN><<<cdiv(NN * 64, 256), 256, 0, stream>>>(acc6, W1, b1, dinv, ya);

    // layers 2,3 fused (scaled), ping-pong; layer 4 fused + head, 50k nodes only
    k_layer64f<false><<<NN / 8, 512, 0, stream>>>(ya, dinv, row_ptr, epack, W2, b2, yb,
                                                  nullptr, nullptr, nullptr);
    k_layer64f<false><<<NN / 8, 512, 0, stream>>>(yb, dinv, row_ptr, epack, W3, b3, ya,
                                                  nullptr, nullptr, nullptr);
    k_layer64f<true><<<NGNB / 8, 512, 0, stream>>>(ya, dinv, row_ptr, epack, W4, b4, nullptr,
                                                   Wl, bl, out);
}

// Round 8
// 554.452 us; speedup vs baseline: 6.3129x; 1.0395x over previous
//
#include <hip/hip_runtime.h>
#include <hip/hip_fp16.h>

#define NN 100000
#define EE 3200000
#define HH 64
#define FINN 6
#define FOUT 5
#define NGNB 50000
#define NBUK 391   // buckets of 256 nodes: bucket = dst >> 8
#define NBH 64     // blocks for hist/scatter passes

static inline int cdiv(int a, int b) { return (a + b - 1) / b; }
static inline size_t alignup(size_t x) { return (x + 255) & ~(size_t)255; }

// Pass A: per-block bucket histogram (LDS), write blockhist[block][NBUK]
__global__ __launch_bounds__(1024) void k_histA(const int* __restrict__ dst,
                                                int* __restrict__ blockhist) {
    __shared__ int hist[NBUK];
    int t = threadIdx.x;
    if (t < NBUK) hist[t] = 0;
    __syncthreads();
    for (int e = blockIdx.x * 1024 + t; e < EE; e += NBH * 1024)
        atomicAdd(&hist[dst[e] >> 8], 1);
    __syncthreads();
    if (t < NBUK) blockhist[blockIdx.x * NBUK + t] = hist[t];
}

// Pass B: turn blockhist into per-(block,bucket) bases; bucket_ptr = bucket starts
__global__ void k_scanB(int* __restrict__ blockhist, int* __restrict__ bucket_ptr) {
    __shared__ int sh[512];
    int t = threadIdx.x;
    int total = 0;
    if (t < NBUK)
        for (int b = 0; b < NBH; ++b) total += blockhist[b * NBUK + t];
    sh[t] = (t < NBUK) ? total : 0;
    __syncthreads();
    for (int off = 1; off < 512; off <<= 1) {
        int a = (t >= off) ? sh[t - off] : 0;
        __syncthreads();
        sh[t] += a;
        __syncthreads();
    }
    if (t < NBUK) {
        int base = sh[t] - total;  // exclusive
        bucket_ptr[t] = base;
        if (t == 0) bucket_ptr[NBUK] = EE;
        int run = base;
        for (int b = 0; b < NBH; ++b) {
            int c = blockhist[b * NBUK + t];
            blockhist[b * NBUK + t] = run;
            run += c;
        }
    }
}

// Pass C: scatter edges into bucket-grouped ebuk = {(dl<<17)|src, w}
__global__ __launch_bounds__(1024) void k_scatC(const int* __restrict__ src,
                                                const int* __restrict__ dst,
                                                const float* __restrict__ w,
                                                const int* __restrict__ blockhist,
                                                int2* __restrict__ ebuk) {
    __shared__ int cur[NBUK];
    int t = threadIdx.x;
    if (t < NBUK) cur[t] = blockhist[blockIdx.x * NBUK + t];
    __syncthreads();
    for (int e = blockIdx.x * 1024 + t; e < EE; e += NBH * 1024) {
        int d = dst[e];
        int k = d >> 8, dl = d & 255;
        int pos = atomicAdd(&cur[k], 1);
        int2 p;
        p.x = (dl << 17) | src[e];
        p.y = __float_as_int(w[e]);
        ebuk[pos] = p;
    }
}

// Pass D: per-bucket — LDS per-node count + weighted degree, scan, CSR scatter.
__global__ __launch_bounds__(1024) void k_csrD(const int2* __restrict__ ebuk,
                                               const int* __restrict__ bucket_ptr,
                                               int* __restrict__ row_ptr,
                                               float* __restrict__ dinv,
                                               int2* __restrict__ epack) {
    __shared__ int cnt[256];
    __shared__ float wdeg[256];
    __shared__ int sh[256];
    __shared__ int cursor[256];
    int t = threadIdx.x;
    int k = blockIdx.x;
    if (t < 256) { cnt[t] = 0; wdeg[t] = 1.0f; }  // 1.0 = self-loop weight
    __syncthreads();
    int r0 = bucket_ptr[k], r1 = bucket_ptr[k + 1];
    for (int e = r0 + t; e < r1; e += 1024) {
        int2 p = ebuk[e];
        int dl = (p.x >> 17) & 255;
        atomicAdd(&cnt[dl], 1);
        atomicAdd(&wdeg[dl], __int_as_float(p.y));
    }
    __syncthreads();
    int c = 0;
    if (t < 256) { c = cnt[t]; sh[t] = c; }
    __syncthreads();
    for (int off = 1; off < 256; off <<= 1) {
        int a = (t < 256 && t >= off) ? sh[t - off] : 0;
        __syncthreads();
        if (t < 256) sh[t] += a;
        __syncthreads();
    }
    if (t < 256) {
        int gstart = r0 + sh[t] - c;
        cursor[t] = gstart;
        int node = k * 256 + t;
        if (node < NN) {
            row_ptr[node] = gstart;
            dinv[node] = rsqrtf(wdeg[t]);
            if (node == NN - 1) row_ptr[NN] = EE;
        }
    }
    __syncthreads();
    for (int e = r0 + t; e < r1; e += 1024) {
        int2 p = ebuk[e];
        int dl = (p.x >> 17) & 255;
        int pos = atomicAdd(&cursor[dl], 1);
        int2 q;
        q.x = p.x & 0x1FFFF;
        q.y = p.y;
        epack[pos] = q;
    }
}

// vfs[i,f] = vf[i,f] * dinv[i]
__global__ void k_vfs(const float* __restrict__ vf, const float* __restrict__ dinv,
                      float* __restrict__ vfs) {
    int i = blockIdx.x * 256 + threadIdx.x;
    if (i >= NN) return;
    float di = dinv[i];
#pragma unroll
    for (int f = 0; f < FINN; ++f) vfs[i * FINN + f] = vf[i * FINN + f] * di;
}

// layer-1 aggregation: acc6[i] = dinv[i] * (vfs[i] + sum w * vfs[s])
__global__ void k_gather6(const float* __restrict__ vfs, const float* __restrict__ dinv,
                          const int* __restrict__ rp, const int2* __restrict__ epack,
                          float* __restrict__ acc6) {
    int i = blockIdx.x * 256 + threadIdx.x;
    if (i >= NN) return;
    float av[FINN];
#pragma unroll
    for (int f = 0; f < FINN; ++f) av[f] = vfs[i * FINN + f];
    int e1 = rp[i + 1];
    for (int e = rp[i]; e < e1; ++e) {
        int2 p = epack[e];
        float wn = __int_as_float(p.y);
#pragma unroll
        for (int f = 0; f < FINN; ++f) av[f] += vfs[p.x * FINN + f] * wn;
    }
    float di = dinv[i];
#pragma unroll
    for (int f = 0; f < FINN; ++f) acc6[i * FINN + f] = av[f] * di;
}

// Fused 64-dim layer: wave per node, 8 nodes/block.
// Row-PAIR gather: lane covers feature pair fp=lane&31 via __half2; wave half
// hf=lane>>5 takes even/odd edges -> one VMEM fetches two rows; unroll 4 pairs
// keeps 8 cache lines in flight. Edge records via wave-uniform scalar loads.
// Epilogue: in-LDS 64->64 GEMM + bias + sigmoid. HEAD: only NGNB nodes,
// fused 64->5 head, writes out directly.
template <bool HEAD>
__global__ __launch_bounds__(512) void k_layer64f(
    const __half* __restrict__ yin, const float* __restrict__ dinv,
    const int* __restrict__ rp, const int2* __restrict__ epack,
    const float* __restrict__ W, const float* __restrict__ b,
    __half* __restrict__ yout,
    const float* __restrict__ Wl, const float* __restrict__ bl,
    float* __restrict__ outp) {
    __shared__ float Wsh[HH * HH];   // 16 KB
    __shared__ float bsh[HH];
    __shared__ float aggsh[8 * HH];
    __shared__ float Wlsh[HH * FOUT];
    __shared__ float blsh[FOUT];
    for (int t = threadIdx.x; t < HH * HH; t += 512) Wsh[t] = W[t];
    if (threadIdx.x < HH) bsh[threadIdx.x] = b[threadIdx.x];
    if (HEAD) {
        for (int t = threadIdx.x; t < HH * FOUT; t += 512) Wlsh[t] = Wl[t];
        if (threadIdx.x < FOUT) blsh[threadIdx.x] = bl[threadIdx.x];
    }

    int wv = threadIdx.x >> 6, lane = threadIdx.x & 63;
    int i = blockIdx.x * 8 + wv;  // grids divide exactly: no partial blocks
    int hf = lane >> 5, fp = lane & 31;
    float di = dinv[i];
    const __half2* y2 = (const __half2*)yin;
    float2 a = make_float2(0.0f, 0.0f);
    if (hf == 0) {  // self loop (coeff 1), even half only
        float2 sv = __half22float2(y2[(size_t)i * 32 + fp]);
        a.x = sv.x;
        a.y = sv.y;
    }
    int e0 = __builtin_amdgcn_readfirstlane(rp[i]);
    int e1 = __builtin_amdgcn_readfirstlane(rp[i + 1]);
    int e = e0;
    for (; e + 8 <= e1; e += 8) {  // 4 pairs = 8 rows in flight
        int2 q0 = epack[e + 0], q1 = epack[e + 1];
        int2 q2 = epack[e + 2], q3 = epack[e + 3];
        int2 q4 = epack[e + 4], q5 = epack[e + 5];
        int2 q6 = epack[e + 6], q7 = epack[e + 7];
        int s0 = hf ? q1.x : q0.x;  float w0 = __int_as_float(hf ? q1.y : q0.y);
        int s1 = hf ? q3.x : q2.x;  float w1 = __int_as_float(hf ? q3.y : q2.y);
        int s2 = hf ? q5.x : q4.x;  float w2 = __int_as_float(hf ? q5.y : q4.y);
        int s3 = hf ? q7.x : q6.x;  float w3 = __int_as_float(hf ? q7.y : q6.y);
        float2 v0 = __half22float2(y2[(size_t)s0 * 32 + fp]);
        float2 v1 = __half22float2(y2[(size_t)s1 * 32 + fp]);
        float2 v2 = __half22float2(y2[(size_t)s2 * 32 + fp]);
        float2 v3 = __half22float2(y2[(size_t)s3 * 32 + fp]);
        a.x += v0.x * w0; a.y += v0.y * w0;
        a.x += v1.x * w1; a.y += v1.y * w1;
        a.x += v2.x * w2; a.y += v2.y * w2;
        a.x += v3.x * w3; a.y += v3.y * w3;
    }
    for (; e + 2 <= e1; e += 2) {
        int2 qa = epack[e], qb = epack[e + 1];
        int s = hf ? qb.x : qa.x;
        float wn = __int_as_float(hf ? qb.y : qa.y);
        float2 v = __half22float2(y2[(size_t)s * 32 + fp]);
        a.x += v.x * wn;
        a.y += v.y * wn;
    }
    if (e < e1 && hf == 0) {  // odd tail edge: even half takes it
        int2 q = epack[e];
        float wn = __int_as_float(q.y);
        float2 v = __half22float2(y2[(size_t)q.x * 32 + fp]);
        a.x += v.x * wn;
        a.y += v.y * wn;
    }
    a.x += __shfl(a.x, lane ^ 32, 64);
    a.y += __shfl(a.y, lane ^ 32, 64);
    __syncthreads();  // Wsh/bsh staged
    if (hf == 0)
        ((float2*)&aggsh[wv * HH])[fp] = make_float2(a.x * di, a.y * di);
    __syncthreads();
    float o = bsh[lane];
    const float4* a4 = (const float4*)&aggsh[wv * HH];
#pragma unroll
    for (int f0 = 0; f0 < HH; f0 += 4) {
        float4 av = a4[f0 >> 2];  // broadcast read
        o += av.x * Wsh[(f0 + 0) * HH + lane];
        o += av.y * Wsh[(f0 + 1) * HH + lane];
        o += av.z * Wsh[(f0 + 2) * HH + lane];
        o += av.w * Wsh[(f0 + 3) * HH + lane];
    }
    float sig = 1.0f / (1.0f + __expf(-o));
    if (!HEAD) {
        yout[(size_t)i * HH + lane] = __float2half(sig * di);  // scaled y
    } else {
        aggsh[wv * HH + lane] = sig;  // unscaled, own-wave slice only
        __syncthreads();
        if (lane < FOUT) {
            float s = blsh[lane];
            const float* ar = &aggsh[wv * HH];
#pragma unroll
            for (int f = 0; f < HH; ++f) s += ar[f] * Wlsh[f * FOUT + lane];
            outp[(size_t)i * FOUT + lane] = s;
        }
    }
}

// out[i,:] = sigmoid(acc6[i,:FI] @ W + b) * dinv  (layer 1 only)
template <int FI>
__global__ void k_gemm_sig(const float* __restrict__ x, const float* __restrict__ W,
                           const float* __restrict__ b, const float* __restrict__ dinv,
                           __half* __restrict__ out) {
    __shared__ float Wsl[FI * 64];
    __shared__ float bsl[64];
    for (int t = threadIdx.x; t < FI * 64; t += 256) Wsl[t] = W[t];
    if (threadIdx.x < 64) bsl[threadIdx.x] = b[threadIdx.x];
    __syncthreads();
    int wave = (blockIdx.x * 256 + threadIdx.x) >> 6;
    int lane = threadIdx.x & 63;
    if (wave >= NN) return;
    const float* xr = x + (size_t)wave * FI;
    float s = bsl[lane];
#pragma unroll
    for (int f = 0; f < FI; ++f) s += xr[f] * Wsl[f * 64 + lane];
    float sig = 1.0f / (1.0f + __expf(-s));
    sig *= dinv[wave];
    out[(size_t)wave * HH + lane] = __float2half(sig);
}

extern "C" void kernel_launch(void* const* d_in, const int* in_sizes, int n_in,
                              void* d_out, int out_size, void* d_ws, size_t ws_size,
                              hipStream_t stream) {
    (void)in_sizes; (void)n_in; (void)out_size; (void)ws_size;
    const float* vf = (const float*)d_in[0];
    const int* edges = (const int*)d_in[1];
    const float* w = (const float*)d_in[2];
    const float* W1 = (const float*)d_in[3];
    const float* b1 = (const float*)d_in[4];
    const float* W2 = (const float*)d_in[5];
    const float* b2 = (const float*)d_in[6];
    const float* W3 = (const float*)d_in[7];
    const float* b3 = (const float*)d_in[8];
    const float* W4 = (const float*)d_in[9];
    const float* b4 = (const float*)d_in[10];
    const float* Wl = (const float*)d_in[11];
    const float* bl = (const float*)d_in[12];
    float* out = (float*)d_out;

    const int* src = edges;
    const int* dst = edges + EE;

    // workspace: 256B-aligned regions
    char* base = (char*)d_ws;
    size_t off = 0;
    float* dinv = (float*)(base + off);      off = alignup(off + sizeof(float) * NN);
    int* row_ptr = (int*)(base + off);       off = alignup(off + sizeof(int) * (NN + 1));
    int* bucket_ptr = (int*)(base + off);    off = alignup(off + sizeof(int) * (NBUK + 1));
    int* blockhist = (int*)(base + off);     off = alignup(off + sizeof(int) * NBH * NBUK);
    int2* ebuk = (int2*)(base + off);        off = alignup(off + sizeof(int2) * EE);
    int2* epack = (int2*)(base + off);       off = alignup(off + sizeof(int2) * EE);
    float* acc6 = (float*)(base + off);      off = alignup(off + sizeof(float) * (size_t)NN * FINN);
    float* vfs = (float*)(base + off);       off = alignup(off + sizeof(float) * (size_t)NN * FINN);
    __half* ya = (__half*)(base + off);      off = alignup(off + sizeof(__half) * (size_t)NN * HH);
    __half* yb = (__half*)(base + off);      off = alignup(off + sizeof(__half) * (size_t)NN * HH);

    // CSR build via two-level bucket sort (no global atomics)
    k_histA<<<NBH, 1024, 0, stream>>>(dst, blockhist);
    k_scanB<<<1, 512, 0, stream>>>(blockhist, bucket_ptr);
    k_scatC<<<NBH, 1024, 0, stream>>>(src, dst, w, blockhist, ebuk);
    k_csrD<<<NBUK, 1024, 0, stream>>>(ebuk, bucket_ptr, row_ptr, dinv, epack);

    // scaled input features
    k_vfs<<<cdiv(NN, 256), 256, 0, stream>>>(vf, dinv, vfs);

    // layer 1: gather(6) -> gemm+sigmoid (scaled -> ya)
    k_gather6<<<cdiv(NN, 256), 256, 0, stream>>>(vfs, dinv, row_ptr, epack, acc6);
    k_gemm_sig<FINN><<<cdiv(NN * 64, 256), 256, 0, stream>>>(acc6, W1, b1, dinv, ya);

    // layers 2,3 fused (scaled), ping-pong; layer 4 fused + head, 50k nodes only
    k_layer64f<false><<<NN / 8, 512, 0, stream>>>(ya, dinv, row_ptr, epack, W2, b2, yb,
                                                  nullptr, nullptr, nullptr);
    k_layer64f<false><<<NN / 8, 512, 0, stream>>>(yb, dinv, row_ptr, epack, W3, b3, ya,
                                                  nullptr, nullptr, nullptr);
    k_layer64f<true><<<NGNB / 8, 512, 0, stream>>>(ya, dinv, row_ptr, epack, W4, b4, nullptr,
                                                   Wl, bl, out);
}

// Round 9
// 515.498 us; speedup vs baseline: 6.7899x; 1.0756x over previous
//
#include <hip/hip_runtime.h>
#include <hip/hip_fp16.h>

#define NN 100000
#define EE 3200000
#define HH 64
#define FINN 6
#define FOUT 5
#define NGNB 50000
#define NBUK 391   // buckets of 256 nodes: bucket = dst >> 8
#define NBH 64     // blocks for hist/scatter passes

static inline int cdiv(int a, int b) { return (a + b - 1) / b; }
static inline size_t alignup(size_t x) { return (x + 255) & ~(size_t)255; }

// Pass A: per-block bucket histogram (LDS), write blockhist[block][NBUK]
__global__ __launch_bounds__(1024) void k_histA(const int* __restrict__ dst,
                                                int* __restrict__ blockhist) {
    __shared__ int hist[NBUK];
    int t = threadIdx.x;
    if (t < NBUK) hist[t] = 0;
    __syncthreads();
    for (int e = blockIdx.x * 1024 + t; e < EE; e += NBH * 1024)
        atomicAdd(&hist[dst[e] >> 8], 1);
    __syncthreads();
    if (t < NBUK) blockhist[blockIdx.x * NBUK + t] = hist[t];
}

// Pass B: turn blockhist into per-(block,bucket) bases; bucket_ptr = bucket starts
__global__ void k_scanB(int* __restrict__ blockhist, int* __restrict__ bucket_ptr) {
    __shared__ int sh[512];
    int t = threadIdx.x;
    int total = 0;
    if (t < NBUK)
        for (int b = 0; b < NBH; ++b) total += blockhist[b * NBUK + t];
    sh[t] = (t < NBUK) ? total : 0;
    __syncthreads();
    for (int off = 1; off < 512; off <<= 1) {
        int a = (t >= off) ? sh[t - off] : 0;
        __syncthreads();
        sh[t] += a;
        __syncthreads();
    }
    if (t < NBUK) {
        int base = sh[t] - total;  // exclusive
        bucket_ptr[t] = base;
        if (t == 0) bucket_ptr[NBUK] = EE;
        int run = base;
        for (int b = 0; b < NBH; ++b) {
            int c = blockhist[b * NBUK + t];
            blockhist[b * NBUK + t] = run;
            run += c;
        }
    }
}

// Pass C: scatter edges into bucket-grouped ebuk = {(dl<<17)|src, w}
__global__ __launch_bounds__(1024) void k_scatC(const int* __restrict__ src,
                                                const int* __restrict__ dst,
                                                const float* __restrict__ w,
                                                const int* __restrict__ blockhist,
                                                int2* __restrict__ ebuk) {
    __shared__ int cur[NBUK];
    int t = threadIdx.x;
    if (t < NBUK) cur[t] = blockhist[blockIdx.x * NBUK + t];
    __syncthreads();
    for (int e = blockIdx.x * 1024 + t; e < EE; e += NBH * 1024) {
        int d = dst[e];
        int k = d >> 8, dl = d & 255;
        int pos = atomicAdd(&cur[k], 1);
        int2 p;
        p.x = (dl << 17) | src[e];
        p.y = __float_as_int(w[e]);
        ebuk[pos] = p;
    }
}

// Pass D: per-bucket — LDS per-node count + weighted degree, scan, CSR scatter.
// epack.x = src * 128 (byte offset of the fp16 row), epack.y = w bits.
__global__ __launch_bounds__(1024) void k_csrD(const int2* __restrict__ ebuk,
                                               const int* __restrict__ bucket_ptr,
                                               int* __restrict__ row_ptr,
                                               float* __restrict__ dinv,
                                               int2* __restrict__ epack) {
    __shared__ int cnt[256];
    __shared__ float wdeg[256];
    __shared__ int sh[256];
    __shared__ int cursor[256];
    int t = threadIdx.x;
    int k = blockIdx.x;
    if (t < 256) { cnt[t] = 0; wdeg[t] = 1.0f; }  // 1.0 = self-loop weight
    __syncthreads();
    int r0 = bucket_ptr[k], r1 = bucket_ptr[k + 1];
    for (int e = r0 + t; e < r1; e += 1024) {
        int2 p = ebuk[e];
        int dl = (p.x >> 17) & 255;
        atomicAdd(&cnt[dl], 1);
        atomicAdd(&wdeg[dl], __int_as_float(p.y));
    }
    __syncthreads();
    int c = 0;
    if (t < 256) { c = cnt[t]; sh[t] = c; }
    __syncthreads();
    for (int off = 1; off < 256; off <<= 1) {
        int a = (t < 256 && t >= off) ? sh[t - off] : 0;
        __syncthreads();
        if (t < 256) sh[t] += a;
        __syncthreads();
    }
    if (t < 256) {
        int gstart = r0 + sh[t] - c;
        cursor[t] = gstart;
        int node = k * 256 + t;
        if (node < NN) {
            row_ptr[node] = gstart;
            dinv[node] = rsqrtf(wdeg[t]);
            if (node == NN - 1) row_ptr[NN] = EE;
        }
    }
    __syncthreads();
    for (int e = r0 + t; e < r1; e += 1024) {
        int2 p = ebuk[e];
        int dl = (p.x >> 17) & 255;
        int pos = atomicAdd(&cursor[dl], 1);
        int2 q;
        q.x = (p.x & 0x1FFFF) << 7;  // src * 128 bytes
        q.y = p.y;
        epack[pos] = q;
    }
}

// vfs[i,f] = vf[i,f] * dinv[i]
__global__ void k_vfs(const float* __restrict__ vf, const float* __restrict__ dinv,
                      float* __restrict__ vfs) {
    int i = blockIdx.x * 256 + threadIdx.x;
    if (i >= NN) return;
    float di = dinv[i];
#pragma unroll
    for (int f = 0; f < FINN; ++f) vfs[i * FINN + f] = vf[i * FINN + f] * di;
}

// layer-1 aggregation: acc6[i] = dinv[i] * (vfs[i] + sum w * vfs[s])
__global__ void k_gather6(const float* __restrict__ vfs, const float* __restrict__ dinv,
                          const int* __restrict__ rp, const int2* __restrict__ epack,
                          float* __restrict__ acc6) {
    int i = blockIdx.x * 256 + threadIdx.x;
    if (i >= NN) return;
    float av[FINN];
#pragma unroll
    for (int f = 0; f < FINN; ++f) av[f] = vfs[i * FINN + f];
    int e1 = rp[i + 1];
    for (int e = rp[i]; e < e1; ++e) {
        int2 p = epack[e];
        int s = p.x >> 7;
        float wn = __int_as_float(p.y);
#pragma unroll
        for (int f = 0; f < FINN; ++f) av[f] += vfs[s * FINN + f] * wn;
    }
    float di = dinv[i];
#pragma unroll
    for (int f = 0; f < FINN; ++f) acc6[i * FINN + f] = av[f] * di;
}

// Fused 64-dim layer: wave per node, 8 nodes/block.
// Gather loop: 64-edge chunks staged into wave-private LDS (coalesced load +
// ds_write, no barrier needed within a wave); pair loop reads records via
// 2-address-broadcast ds_read_b64 (free); epack.x is the pre-scaled row byte
// offset so each row-pair load is 1 v_add + 1 saddr global_load_dword; the
// accumulate is fmaf(fpext(f16),f32,f32) -> v_fma_mix_f32.
// Epilogue: in-LDS 64->64 GEMM + bias + sigmoid. HEAD: only NGNB nodes,
// fused 64->5 head, writes out directly.
template <bool HEAD>
__global__ __launch_bounds__(512) void k_layer64f(
    const __half* __restrict__ yin, const float* __restrict__ dinv,
    const int* __restrict__ rp, const int2* __restrict__ epack,
    const float* __restrict__ W, const float* __restrict__ b,
    __half* __restrict__ yout,
    const float* __restrict__ Wl, const float* __restrict__ bl,
    float* __restrict__ outp) {
    __shared__ float Wsh[HH * HH];   // 16 KB
    __shared__ float bsh[HH];
    __shared__ float aggsh[8 * HH];
    __shared__ float Wlsh[HH * FOUT];
    __shared__ float blsh[FOUT];
    __shared__ int2 estage[8 * 64];  // 512 B wave-private edge staging per wave
    for (int t = threadIdx.x; t < HH * HH; t += 512) Wsh[t] = W[t];
    if (threadIdx.x < HH) bsh[threadIdx.x] = b[threadIdx.x];
    if (HEAD) {
        for (int t = threadIdx.x; t < HH * FOUT; t += 512) Wlsh[t] = Wl[t];
        if (threadIdx.x < FOUT) blsh[threadIdx.x] = bl[threadIdx.x];
    }

    int wv = threadIdx.x >> 6, lane = threadIdx.x & 63;
    int i = blockIdx.x * 8 + wv;  // grids divide exactly: no partial blocks
    int hf = lane >> 5, fp = lane & 31;
    unsigned fp4 = (unsigned)fp * 4u;
    float di = dinv[i];
    const char* yb = (const char*)yin;
    float2 a = make_float2(0.0f, 0.0f);
    if (hf == 0) {  // self loop (coeff 1), even half only
        unsigned vpk = *(const unsigned*)(yb + (size_t)i * 128 + fp4);
        __half2 h = *(__half2*)&vpk;
        a.x = __half2float(h.x);
        a.y = __half2float(h.y);
    }
    int e0 = __builtin_amdgcn_readfirstlane(rp[i]);
    int e1 = __builtin_amdgcn_readfirstlane(rp[i + 1]);
    int2* sw = &estage[wv * 64];
    for (int base = e0; base < e1; base += 64) {
        int n = e1 - base;
        if (n > 64) n = 64;
        if (lane < n) sw[lane] = epack[base + lane];  // coalesced 512B/wave
        int n2 = n & ~1;
        int j = 0;
        for (; j + 8 <= n2; j += 8) {  // 4 pairs = 8 rows in flight
            int2 r0 = sw[j + 0 + hf];
            int2 r1 = sw[j + 2 + hf];
            int2 r2 = sw[j + 4 + hf];
            int2 r3 = sw[j + 6 + hf];
            unsigned v0 = *(const unsigned*)(yb + ((unsigned)r0.x + fp4));
            unsigned v1 = *(const unsigned*)(yb + ((unsigned)r1.x + fp4));
            unsigned v2 = *(const unsigned*)(yb + ((unsigned)r2.x + fp4));
            unsigned v3 = *(const unsigned*)(yb + ((unsigned)r3.x + fp4));
            float w0 = __int_as_float(r0.y), w1 = __int_as_float(r1.y);
            float w2 = __int_as_float(r2.y), w3 = __int_as_float(r3.y);
            __half2 h0 = *(__half2*)&v0, h1 = *(__half2*)&v1;
            __half2 h2 = *(__half2*)&v2, h3 = *(__half2*)&v3;
            a.x = fmaf(__half2float(h0.x), w0, a.x);
            a.y = fmaf(__half2float(h0.y), w0, a.y);
            a.x = fmaf(__half2float(h1.x), w1, a.x);
            a.y = fmaf(__half2float(h1.y), w1, a.y);
            a.x = fmaf(__half2float(h2.x), w2, a.x);
            a.y = fmaf(__half2float(h2.y), w2, a.y);
            a.x = fmaf(__half2float(h3.x), w3, a.x);
            a.y = fmaf(__half2float(h3.y), w3, a.y);
        }
        for (; j < n2; j += 2) {
            int2 r = sw[j + hf];
            unsigned v = *(const unsigned*)(yb + ((unsigned)r.x + fp4));
            float wn = __int_as_float(r.y);
            __half2 h = *(__half2*)&v;
            a.x = fmaf(__half2float(h.x), wn, a.x);
            a.y = fmaf(__half2float(h.y), wn, a.y);
        }
        if (n2 < n && hf == 0) {  // odd tail edge: even half takes it
            int2 r = sw[n2];
            unsigned v = *(const unsigned*)(yb + ((unsigned)r.x + fp4));
            float wn = __int_as_float(r.y);
            __half2 h = *(__half2*)&v;
            a.x = fmaf(__half2float(h.x), wn, a.x);
            a.y = fmaf(__half2float(h.y), wn, a.y);
        }
    }
    a.x += __shfl(a.x, lane ^ 32, 64);
    a.y += __shfl(a.y, lane ^ 32, 64);
    __syncthreads();  // Wsh/bsh staged
    if (hf == 0)
        ((float2*)&aggsh[wv * HH])[fp] = make_float2(a.x * di, a.y * di);
    __syncthreads();
    float o = bsh[lane];
    const float4* a4 = (const float4*)&aggsh[wv * HH];
#pragma unroll
    for (int f0 = 0; f0 < HH; f0 += 4) {
        float4 av = a4[f0 >> 2];  // broadcast read
        o += av.x * Wsh[(f0 + 0) * HH + lane];
        o += av.y * Wsh[(f0 + 1) * HH + lane];
        o += av.z * Wsh[(f0 + 2) * HH + lane];
        o += av.w * Wsh[(f0 + 3) * HH + lane];
    }
    float sig = 1.0f / (1.0f + __expf(-o));
    if (!HEAD) {
        yout[(size_t)i * HH + lane] = __float2half(sig * di);  // scaled y
    } else {
        aggsh[wv * HH + lane] = sig;  // unscaled, own-wave slice only
        __syncthreads();
        if (lane < FOUT) {
            float s = blsh[lane];
            const float* ar = &aggsh[wv * HH];
#pragma unroll
            for (int f = 0; f < HH; ++f) s += ar[f] * Wlsh[f * FOUT + lane];
            outp[(size_t)i * FOUT + lane] = s;
        }
    }
}

// out[i,:] = sigmoid(acc6[i,:FI] @ W + b) * dinv  (layer 1 only)
template <int FI>
__global__ void k_gemm_sig(const float* __restrict__ x, const float* __restrict__ W,
                           const float* __restrict__ b, const float* __restrict__ dinv,
                           __half* __restrict__ out) {
    __shared__ float Wsl[FI * 64];
    __shared__ float bsl[64];
    for (int t = threadIdx.x; t < FI * 64; t += 256) Wsl[t] = W[t];
    if (threadIdx.x < 64) bsl[threadIdx.x] = b[threadIdx.x];
    __syncthreads();
    int wave = (blockIdx.x * 256 + threadIdx.x) >> 6;
    int lane = threadIdx.x & 63;
    if (wave >= NN) return;
    const float* xr = x + (size_t)wave * FI;
    float s = bsl[lane];
#pragma unroll
    for (int f = 0; f < FI; ++f) s += xr[f] * Wsl[f * 64 + lane];
    float sig = 1.0f / (1.0f + __expf(-s));
    sig *= dinv[wave];
    out[(size_t)wave * HH + lane] = __float2half(sig);
}

extern "C" void kernel_launch(void* const* d_in, const int* in_sizes, int n_in,
                              void* d_out, int out_size, void* d_ws, size_t ws_size,
                              hipStream_t stream) {
    (void)in_sizes; (void)n_in; (void)out_size; (void)ws_size;
    const float* vf = (const float*)d_in[0];
    const int* edges = (const int*)d_in[1];
    const float* w = (const float*)d_in[2];
    const float* W1 = (const float*)d_in[3];
    const float* b1 = (const float*)d_in[4];
    const float* W2 = (const float*)d_in[5];
    const float* b2 = (const float*)d_in[6];
    const float* W3 = (const float*)d_in[7];
    const float* b3 = (const float*)d_in[8];
    const float* W4 = (const float*)d_in[9];
    const float* b4 = (const float*)d_in[10];
    const float* Wl = (const float*)d_in[11];
    const float* bl = (const float*)d_in[12];
    float* out = (float*)d_out;

    const int* src = edges;
    const int* dst = edges + EE;

    // workspace: 256B-aligned regions
    char* base = (char*)d_ws;
    size_t off = 0;
    float* dinv = (float*)(base + off);      off = alignup(off + sizeof(float) * NN);
    int* row_ptr = (int*)(base + off);       off = alignup(off + sizeof(int) * (NN + 1));
    int* bucket_ptr = (int*)(base + off);    off = alignup(off + sizeof(int) * (NBUK + 1));
    int* blockhist = (int*)(base + off);     off = alignup(off + sizeof(int) * NBH * NBUK);
    int2* ebuk = (int2*)(base + off);        off = alignup(off + sizeof(int2) * EE);
    int2* epack = (int2*)(base + off);       off = alignup(off + sizeof(int2) * EE);
    float* acc6 = (float*)(base + off);      off = alignup(off + sizeof(float) * (size_t)NN * FINN);
    float* vfs = (float*)(base + off);       off = alignup(off + sizeof(float) * (size_t)NN * FINN);
    __half* ya = (__half*)(base + off);      off = alignup(off + sizeof(__half) * (size_t)NN * HH);
    __half* yb = (__half*)(base + off);      off = alignup(off + sizeof(__half) * (size_t)NN * HH);

    // CSR build via two-level bucket sort (no global atomics)
    k_histA<<<NBH, 1024, 0, stream>>>(dst, blockhist);
    k_scanB<<<1, 512, 0, stream>>>(blockhist, bucket_ptr);
    k_scatC<<<NBH, 1024, 0, stream>>>(src, dst, w, blockhist, ebuk);
    k_csrD<<<NBUK, 1024, 0, stream>>>(ebuk, bucket_ptr, row_ptr, dinv, epack);

    // scaled input features
    k_vfs<<<cdiv(NN, 256), 256, 0, stream>>>(vf, dinv, vfs);

    // layer 1: gather(6) -> gemm+sigmoid (scaled -> ya)
    k_gather6<<<cdiv(NN, 256), 256, 0, stream>>>(vfs, dinv, row_ptr, epack, acc6);
    k_gemm_sig<FINN><<<cdiv(NN * 64, 256), 256, 0, stream>>>(acc6, W1, b1, dinv, ya);

    // layers 2,3 fused (scaled), ping-pong; layer 4 fused + head, 50k nodes only
    k_layer64f<false><<<NN / 8, 512, 0, stream>>>(ya, dinv, row_ptr, epack, W2, b2, yb,
                                                  nullptr, nullptr, nullptr);
    k_layer64f<false><<<NN / 8, 512, 0, stream>>>(yb, dinv, row_ptr, epack, W3, b3, ya,
                                                  nullptr, nullptr, nullptr);
    k_layer64f<true><<<NGNB / 8, 512, 0, stream>>>(ya, dinv, row_ptr, epack, W4, b4, nullptr,
                                                   Wl, bl, out);
}

// Round 10
// 477.100 us; speedup vs baseline: 7.3364x; 1.0805x over previous
//
#include <hip/hip_runtime.h>
#include <hip/hip_fp16.h>

#define NN 100000
#define EE 3200000
#define HH 64
#define FINN 6
#define FOUT 5
#define NGNB 50000
#define NBUK 391   // buckets of 256 nodes: bucket = dst >> 8
#define NBH 256    // blocks for hist/scatter passes (1 block/CU)

static inline int cdiv(int a, int b) { return (a + b - 1) / b; }
static inline size_t alignup(size_t x) { return (x + 255) & ~(size_t)255; }

// Pass A: per-block bucket histogram (LDS), write blockhist[block][NBUK]
__global__ __launch_bounds__(1024) void k_histA(const int* __restrict__ dst,
                                                int* __restrict__ blockhist) {
    __shared__ int hist[NBUK];
    int t = threadIdx.x;
    if (t < NBUK) hist[t] = 0;
    __syncthreads();
    for (int e = blockIdx.x * 1024 + t; e < EE; e += NBH * 1024)
        atomicAdd(&hist[dst[e] >> 8], 1);
    __syncthreads();
    if (t < NBUK) blockhist[blockIdx.x * NBUK + t] = hist[t];
}

// Pass B: turn blockhist into per-(block,bucket) bases; bucket_ptr = bucket starts
__global__ void k_scanB(int* __restrict__ blockhist, int* __restrict__ bucket_ptr) {
    __shared__ int sh[512];
    int t = threadIdx.x;
    int total = 0;
    if (t < NBUK)
        for (int b = 0; b < NBH; ++b) total += blockhist[b * NBUK + t];
    sh[t] = (t < NBUK) ? total : 0;
    __syncthreads();
    for (int off = 1; off < 512; off <<= 1) {
        int a = (t >= off) ? sh[t - off] : 0;
        __syncthreads();
        sh[t] += a;
        __syncthreads();
    }
    if (t < NBUK) {
        int base = sh[t] - total;  // exclusive
        bucket_ptr[t] = base;
        if (t == 0) bucket_ptr[NBUK] = EE;
        int run = base;
        for (int b = 0; b < NBH; ++b) {
            int c = blockhist[b * NBUK + t];
            blockhist[b * NBUK + t] = run;
            run += c;
        }
    }
}

// Pass C: scatter edges into bucket-grouped ebuk = {(dl<<17)|src, w}
__global__ __launch_bounds__(1024) void k_scatC(const int* __restrict__ src,
                                                const int* __restrict__ dst,
                                                const float* __restrict__ w,
                                                const int* __restrict__ blockhist,
                                                int2* __restrict__ ebuk) {
    __shared__ int cur[NBUK];
    int t = threadIdx.x;
    if (t < NBUK) cur[t] = blockhist[blockIdx.x * NBUK + t];
    __syncthreads();
    for (int e = blockIdx.x * 1024 + t; e < EE; e += NBH * 1024) {
        int d = dst[e];
        int k = d >> 8, dl = d & 255;
        int pos = atomicAdd(&cur[k], 1);
        int2 p;
        p.x = (dl << 17) | src[e];
        p.y = __float_as_int(w[e]);
        ebuk[pos] = p;
    }
}

// Pass D: per-bucket — one u64 LDS atomic per edge packs {count<<40, wsum fixed
// 2^-24}; scan; CSR scatter. epack.x = src*128 (fp16-row byte offset).
__global__ __launch_bounds__(1024) void k_csrD(const int2* __restrict__ ebuk,
                                               const int* __restrict__ bucket_ptr,
                                               int* __restrict__ row_ptr,
                                               float* __restrict__ dinv,
                                               int2* __restrict__ epack) {
    __shared__ unsigned long long pk[256];
    __shared__ int sh[256];
    __shared__ int cursor[256];
    int t = threadIdx.x;
    int k = blockIdx.x;
    if (t < 256) pk[t] = (1ULL << 24);  // self-loop weight 1.0 (fixed point), count 0
    __syncthreads();
    int r0 = bucket_ptr[k], r1 = bucket_ptr[k + 1];
    for (int e = r0 + t; e < r1; e += 1024) {
        int2 p = ebuk[e];
        int dl = (p.x >> 17) & 255;
        unsigned long long add =
            (1ULL << 40) |
            (unsigned long long)(__int_as_float(p.y) * 16777216.0f);
        atomicAdd(&pk[dl], add);
    }
    __syncthreads();
    int c = 0;
    if (t < 256) { c = (int)(pk[t] >> 40); sh[t] = c; }
    __syncthreads();
    for (int off = 1; off < 256; off <<= 1) {
        int a = (t < 256 && t >= off) ? sh[t - off] : 0;
        __syncthreads();
        if (t < 256) sh[t] += a;
        __syncthreads();
    }
    if (t < 256) {
        int gstart = r0 + sh[t] - c;
        cursor[t] = gstart;
        int node = k * 256 + t;
        if (node < NN) {
            float wsum = (float)(pk[t] & 0xFFFFFFFFFFULL) * (1.0f / 16777216.0f);
            row_ptr[node] = gstart;
            dinv[node] = rsqrtf(wsum);
            if (node == NN - 1) row_ptr[NN] = EE;
        }
    }
    __syncthreads();
    for (int e = r0 + t; e < r1; e += 1024) {
        int2 p = ebuk[e];
        int dl = (p.x >> 17) & 255;
        int pos = atomicAdd(&cursor[dl], 1);
        int2 q;
        q.x = (p.x & 0x1FFFF) << 7;  // src * 128 bytes
        q.y = p.y;
        epack[pos] = q;
    }
}

// vfs[i,f] = vf[i,f] * dinv[i]
__global__ void k_vfs(const float* __restrict__ vf, const float* __restrict__ dinv,
                      float* __restrict__ vfs) {
    int i = blockIdx.x * 256 + threadIdx.x;
    if (i >= NN) return;
    float di = dinv[i];
#pragma unroll
    for (int f = 0; f < FINN; ++f) vfs[i * FINN + f] = vf[i * FINN + f] * di;
}

// layer-1 aggregation: acc6[i] = dinv[i] * (vfs[i] + sum w * vfs[s])
__global__ void k_gather6(const float* __restrict__ vfs, const float* __restrict__ dinv,
                          const int* __restrict__ rp, const int2* __restrict__ epack,
                          float* __restrict__ acc6) {
    int i = blockIdx.x * 256 + threadIdx.x;
    if (i >= NN) return;
    float av[FINN];
#pragma unroll
    for (int f = 0; f < FINN; ++f) av[f] = vfs[i * FINN + f];
    int e1 = rp[i + 1];
    for (int e = rp[i]; e < e1; ++e) {
        int2 p = epack[e];
        int s = p.x >> 7;
        float wn = __int_as_float(p.y);
#pragma unroll
        for (int f = 0; f < FINN; ++f) av[f] += vfs[s * FINN + f] * wn;
    }
    float di = dinv[i];
#pragma unroll
    for (int f = 0; f < FINN; ++f) acc6[i * FINN + f] = av[f] * di;
}

// Fused 64-dim layer: wave per node, 8 nodes/block.
// 64-edge chunks staged to wave-private LDS; pair loop: half-wave hf takes
// even/odd edges, lane covers half2 fp; unroll 8 pairs = 16 rows in flight.
// epack.x pre-scaled byte offset -> 1 v_add + saddr load; fma_mix accumulate.
// Epilogue: in-LDS 64->64 GEMM + bias + sigmoid; HEAD fuses the 64->5 head.
template <bool HEAD>
__global__ __launch_bounds__(512) void k_layer64f(
    const __half* __restrict__ yin, const float* __restrict__ dinv,
    const int* __restrict__ rp, const int2* __restrict__ epack,
    const float* __restrict__ W, const float* __restrict__ b,
    __half* __restrict__ yout,
    const float* __restrict__ Wl, const float* __restrict__ bl,
    float* __restrict__ outp) {
    __shared__ float Wsh[HH * HH];   // 16 KB
    __shared__ float bsh[HH];
    __shared__ float aggsh[8 * HH];
    __shared__ float Wlsh[HH * FOUT];
    __shared__ float blsh[FOUT];
    __shared__ int2 estage[8 * 64];  // 512 B wave-private edge staging per wave
    for (int t = threadIdx.x; t < HH * HH; t += 512) Wsh[t] = W[t];
    if (threadIdx.x < HH) bsh[threadIdx.x] = b[threadIdx.x];
    if (HEAD) {
        for (int t = threadIdx.x; t < HH * FOUT; t += 512) Wlsh[t] = Wl[t];
        if (threadIdx.x < FOUT) blsh[threadIdx.x] = bl[threadIdx.x];
    }

    int wv = threadIdx.x >> 6, lane = threadIdx.x & 63;
    int i = blockIdx.x * 8 + wv;  // grids divide exactly: no partial blocks
    int hf = lane >> 5, fp = lane & 31;
    unsigned fp4 = (unsigned)fp * 4u;
    float di = dinv[i];
    const char* ybp = (const char*)yin;
    float2 a = make_float2(0.0f, 0.0f);
    if (hf == 0) {  // self loop (coeff 1), even half only
        unsigned vpk = *(const unsigned*)(ybp + (size_t)i * 128 + fp4);
        __half2 h = *(__half2*)&vpk;
        a.x = __half2float(h.x);
        a.y = __half2float(h.y);
    }
    int e0 = __builtin_amdgcn_readfirstlane(rp[i]);
    int e1 = __builtin_amdgcn_readfirstlane(rp[i + 1]);
    int2* sw = &estage[wv * 64];
    for (int base = e0; base < e1; base += 64) {
        int n = e1 - base;
        if (n > 64) n = 64;
        if (lane < n) sw[lane] = epack[base + lane];  // coalesced 512B/wave
        int n2 = n & ~1;
        int j = 0;
        for (; j + 16 <= n2; j += 16) {  // 8 pairs = 16 rows in flight
            int2 r0 = sw[j + 0 + hf],  r1 = sw[j + 2 + hf];
            int2 r2 = sw[j + 4 + hf],  r3 = sw[j + 6 + hf];
            int2 r4 = sw[j + 8 + hf],  r5 = sw[j + 10 + hf];
            int2 r6 = sw[j + 12 + hf], r7 = sw[j + 14 + hf];
            unsigned v0 = *(const unsigned*)(ybp + ((unsigned)r0.x + fp4));
            unsigned v1 = *(const unsigned*)(ybp + ((unsigned)r1.x + fp4));
            unsigned v2 = *(const unsigned*)(ybp + ((unsigned)r2.x + fp4));
            unsigned v3 = *(const unsigned*)(ybp + ((unsigned)r3.x + fp4));
            unsigned v4 = *(const unsigned*)(ybp + ((unsigned)r4.x + fp4));
            unsigned v5 = *(const unsigned*)(ybp + ((unsigned)r5.x + fp4));
            unsigned v6 = *(const unsigned*)(ybp + ((unsigned)r6.x + fp4));
            unsigned v7 = *(const unsigned*)(ybp + ((unsigned)r7.x + fp4));
            __half2 h0 = *(__half2*)&v0, h1 = *(__half2*)&v1;
            __half2 h2 = *(__half2*)&v2, h3 = *(__half2*)&v3;
            __half2 h4 = *(__half2*)&v4, h5 = *(__half2*)&v5;
            __half2 h6 = *(__half2*)&v6, h7 = *(__half2*)&v7;
            float w0 = __int_as_float(r0.y), w1 = __int_as_float(r1.y);
            float w2 = __int_as_float(r2.y), w3 = __int_as_float(r3.y);
            float w4 = __int_as_float(r4.y), w5 = __int_as_float(r5.y);
            float w6 = __int_as_float(r6.y), w7 = __int_as_float(r7.y);
            a.x = fmaf(__half2float(h0.x), w0, a.x);
            a.y = fmaf(__half2float(h0.y), w0, a.y);
            a.x = fmaf(__half2float(h1.x), w1, a.x);
            a.y = fmaf(__half2float(h1.y), w1, a.y);
            a.x = fmaf(__half2float(h2.x), w2, a.x);
            a.y = fmaf(__half2float(h2.y), w2, a.y);
            a.x = fmaf(__half2float(h3.x), w3, a.x);
            a.y = fmaf(__half2float(h3.y), w3, a.y);
            a.x = fmaf(__half2float(h4.x), w4, a.x);
            a.y = fmaf(__half2float(h4.y), w4, a.y);
            a.x = fmaf(__half2float(h5.x), w5, a.x);
            a.y = fmaf(__half2float(h5.y), w5, a.y);
            a.x = fmaf(__half2float(h6.x), w6, a.x);
            a.y = fmaf(__half2float(h6.y), w6, a.y);
            a.x = fmaf(__half2float(h7.x), w7, a.x);
            a.y = fmaf(__half2float(h7.y), w7, a.y);
        }
        for (; j + 8 <= n2; j += 8) {  // 4 pairs
            int2 r0 = sw[j + 0 + hf], r1 = sw[j + 2 + hf];
            int2 r2 = sw[j + 4 + hf], r3 = sw[j + 6 + hf];
            unsigned v0 = *(const unsigned*)(ybp + ((unsigned)r0.x + fp4));
            unsigned v1 = *(const unsigned*)(ybp + ((unsigned)r1.x + fp4));
            unsigned v2 = *(const unsigned*)(ybp + ((unsigned)r2.x + fp4));
            unsigned v3 = *(const unsigned*)(ybp + ((unsigned)r3.x + fp4));
            __half2 h0 = *(__half2*)&v0, h1 = *(__half2*)&v1;
            __half2 h2 = *(__half2*)&v2, h3 = *(__half2*)&v3;
            float w0 = __int_as_float(r0.y), w1 = __int_as_float(r1.y);
            float w2 = __int_as_float(r2.y), w3 = __int_as_float(r3.y);
            a.x = fmaf(__half2float(h0.x), w0, a.x);
            a.y = fmaf(__half2float(h0.y), w0, a.y);
            a.x = fmaf(__half2float(h1.x), w1, a.x);
            a.y = fmaf(__half2float(h1.y), w1, a.y);
            a.x = fmaf(__half2float(h2.x), w2, a.x);
            a.y = fmaf(__half2float(h2.y), w2, a.y);
            a.x = fmaf(__half2float(h3.x), w3, a.x);
            a.y = fmaf(__half2float(h3.y), w3, a.y);
        }
        for (; j < n2; j += 2) {
            int2 r = sw[j + hf];
            unsigned v = *(const unsigned*)(ybp + ((unsigned)r.x + fp4));
            float wn = __int_as_float(r.y);
            __half2 h = *(__half2*)&v;
            a.x = fmaf(__half2float(h.x), wn, a.x);
            a.y = fmaf(__half2float(h.y), wn, a.y);
        }
        if (n2 < n && hf == 0) {  // odd tail edge: even half takes it
            int2 r = sw[n2];
            unsigned v = *(const unsigned*)(ybp + ((unsigned)r.x + fp4));
            float wn = __int_as_float(r.y);
            __half2 h = *(__half2*)&v;
            a.x = fmaf(__half2float(h.x), wn, a.x);
            a.y = fmaf(__half2float(h.y), wn, a.y);
        }
    }
    a.x += __shfl(a.x, lane ^ 32, 64);
    a.y += __shfl(a.y, lane ^ 32, 64);
    __syncthreads();  // Wsh/bsh staged
    if (hf == 0)
        ((float2*)&aggsh[wv * HH])[fp] = make_float2(a.x * di, a.y * di);
    __syncthreads();
    float o = bsh[lane];
    const float4* a4 = (const float4*)&aggsh[wv * HH];
#pragma unroll
    for (int f0 = 0; f0 < HH; f0 += 4) {
        float4 av = a4[f0 >> 2];  // broadcast read
        o += av.x * Wsh[(f0 + 0) * HH + lane];
        o += av.y * Wsh[(f0 + 1) * HH + lane];
        o += av.z * Wsh[(f0 + 2) * HH + lane];
        o += av.w * Wsh[(f0 + 3) * HH + lane];
    }
    float sig = 1.0f / (1.0f + __expf(-o));
    if (!HEAD) {
        yout[(size_t)i * HH + lane] = __float2half(sig * di);  // scaled y
    } else {
        aggsh[wv * HH + lane] = sig;  // unscaled, own-wave slice only
        __syncthreads();
        if (lane < FOUT) {
            float s = blsh[lane];
            const float* ar = &aggsh[wv * HH];
#pragma unroll
            for (int f = 0; f < HH; ++f) s += ar[f] * Wlsh[f * FOUT + lane];
            outp[(size_t)i * FOUT + lane] = s;
        }
    }
}

// out[i,:] = sigmoid(acc6[i,:FI] @ W + b) * dinv  (layer 1 only)
template <int FI>
__global__ void k_gemm_sig(const float* __restrict__ x, const float* __restrict__ W,
                           const float* __restrict__ b, const float* __restrict__ dinv,
                           __half* __restrict__ out) {
    __shared__ float Wsl[FI * 64];
    __shared__ float bsl[64];
    for (int t = threadIdx.x; t < FI * 64; t += 256) Wsl[t] = W[t];
    if (threadIdx.x < 64) bsl[threadIdx.x] = b[threadIdx.x];
    __syncthreads();
    int wave = (blockIdx.x * 256 + threadIdx.x) >> 6;
    int lane = threadIdx.x & 63;
    if (wave >= NN) return;
    const float* xr = x + (size_t)wave * FI;
    float s = bsl[lane];
#pragma unroll
    for (int f = 0; f < FI; ++f) s += xr[f] * Wsl[f * 64 + lane];
    float sig = 1.0f / (1.0f + __expf(-s));
    sig *= dinv[wave];
    out[(size_t)wave * HH + lane] = __float2half(sig);
}

extern "C" void kernel_launch(void* const* d_in, const int* in_sizes, int n_in,
                              void* d_out, int out_size, void* d_ws, size_t ws_size,
                              hipStream_t stream) {
    (void)in_sizes; (void)n_in; (void)out_size; (void)ws_size;
    const float* vf = (const float*)d_in[0];
    const int* edges = (const int*)d_in[1];
    const float* w = (const float*)d_in[2];
    const float* W1 = (const float*)d_in[3];
    const float* b1 = (const float*)d_in[4];
    const float* W2 = (const float*)d_in[5];
    const float* b2 = (const float*)d_in[6];
    const float* W3 = (const float*)d_in[7];
    const float* b3 = (const float*)d_in[8];
    const float* W4 = (const float*)d_in[9];
    const float* b4 = (const float*)d_in[10];
    const float* Wl = (const float*)d_in[11];
    const float* bl = (const float*)d_in[12];
    float* out = (float*)d_out;

    const int* src = edges;
    const int* dst = edges + EE;

    // workspace: 256B-aligned regions
    char* base = (char*)d_ws;
    size_t off = 0;
    float* dinv = (float*)(base + off);      off = alignup(off + sizeof(float) * NN);
    int* row_ptr = (int*)(base + off);       off = alignup(off + sizeof(int) * (NN + 1));
    int* bucket_ptr = (int*)(base + off);    off = alignup(off + sizeof(int) * (NBUK + 1));
    int* blockhist = (int*)(base + off);     off = alignup(off + sizeof(int) * NBH * NBUK);
    int2* ebuk = (int2*)(base + off);        off = alignup(off + sizeof(int2) * EE);
    int2* epack = (int2*)(base + off);       off = alignup(off + sizeof(int2) * EE);
    float* acc6 = (float*)(base + off);      off = alignup(off + sizeof(float) * (size_t)NN * FINN);
    float* vfs = (float*)(base + off);       off = alignup(off + sizeof(float) * (size_t)NN * FINN);
    __half* ya = (__half*)(base + off);      off = alignup(off + sizeof(__half) * (size_t)NN * HH);
    __half* yb = (__half*)(base + off);      off = alignup(off + sizeof(__half) * (size_t)NN * HH);

    // CSR build via two-level bucket sort (no global atomics)
    k_histA<<<NBH, 1024, 0, stream>>>(dst, blockhist);
    k_scanB<<<1, 512, 0, stream>>>(blockhist, bucket_ptr);
    k_scatC<<<NBH, 1024, 0, stream>>>(src, dst, w, blockhist, ebuk);
    k_csrD<<<NBUK, 1024, 0, stream>>>(ebuk, bucket_ptr, row_ptr, dinv, epack);

    // scaled input features
    k_vfs<<<cdiv(NN, 256), 256, 0, stream>>>(vf, dinv, vfs);

    // layer 1: gather(6) -> gemm+sigmoid (scaled -> ya)
    k_gather6<<<cdiv(NN, 256), 256, 0, stream>>>(vfs, dinv, row_ptr, epack, acc6);
    k_gemm_sig<FINN><<<cdiv(NN * 64, 256), 256, 0, stream>>>(acc6, W1, b1, dinv, ya);

    // layers 2,3 fused (scaled), ping-pong; layer 4 fused + head, 50k nodes only
    k_layer64f<false><<<NN / 8, 512, 0, stream>>>(ya, dinv, row_ptr, epack, W2, b2, yb,
                                                  nullptr, nullptr, nullptr);
    k_layer64f<false><<<NN / 8, 512, 0, stream>>>(yb, dinv, row_ptr, epack, W3, b3, ya,
                                                  nullptr, nullptr, nullptr);
    k_layer64f<true><<<NGNB / 8, 512, 0, stream>>>(ya, dinv, row_ptr, epack, W4, b4, nullptr,
                                                   Wl, bl, out);
}